// Round 1
// baseline (1701.464 us; speedup 1.0000x reference)
//
#include <hip/hip_runtime.h>
#include <hip/hip_bf16.h>

#define N_NODES 50000
#define N_EDGES 1600000
#define N_GRAPHS 64

// ---------------------------------------------------------------------------
// CSR build: histogram -> single-block scan -> fill
// ---------------------------------------------------------------------------
__global__ void k_hist(const int* __restrict__ dst, int* __restrict__ counts) {
    int e = blockIdx.x * blockDim.x + threadIdx.x;
    if (e < N_EDGES) atomicAdd(&counts[dst[e]], 1);
}

__global__ void k_scan(int* __restrict__ counts, int* __restrict__ offs) {
    __shared__ int lds[1024];
    const int t = threadIdx.x;
    const int CHUNK = 49;  // 49*1024 = 50176 >= 50000
    int base = t * CHUNK;
    int end = min(base + CHUNK, N_NODES);
    int s = 0;
    for (int i = base; i < end; ++i) s += counts[i];
    lds[t] = s;
    __syncthreads();
    for (int off = 1; off < 1024; off <<= 1) {
        int v = (t >= off) ? lds[t - off] : 0;
        __syncthreads();
        lds[t] += v;
        __syncthreads();
    }
    int run = lds[t] - s;  // exclusive prefix of this chunk
    for (int i = base; i < end; ++i) {
        offs[i] = run;
        run += counts[i];
        counts[i] = 0;  // reset: counts reused as cursor in k_fill
    }
    if (t == 1023) offs[N_NODES] = lds[1023];
}

__global__ void k_fill(const int* __restrict__ src, const int* __restrict__ dst,
                       const int* __restrict__ offs, int* __restrict__ cursor,
                       int* __restrict__ ssrc) {
    int e = blockIdx.x * blockDim.x + threadIdx.x;
    if (e < N_EDGES) {
        int d = dst[e];
        int p = offs[d] + atomicAdd(&cursor[d], 1);
        ssrc[p] = src[e];
    }
}

// ---------------------------------------------------------------------------
// Gather-aggregate (mean): out[n][f] = (1/deg) * sum_{s in N(n)} in[s][f]
// ---------------------------------------------------------------------------
template <int F>
__global__ __launch_bounds__(256) void k_gather(const float* __restrict__ in, int in_stride,
                                                float* __restrict__ out, int out_stride,
                                                const int* __restrict__ offs,
                                                const int* __restrict__ ssrc) {
    constexpr int NPB = 256 / F;
    int n = blockIdx.x * NPB + threadIdx.x / F;
    int f = threadIdx.x % F;
    if (n >= N_NODES) return;
    int s0 = offs[n], s1 = offs[n + 1];
    float a0 = 0.f, a1 = 0.f, a2 = 0.f, a3 = 0.f;
    int i = s0;
    for (; i + 4 <= s1; i += 4) {
        int e0 = ssrc[i], e1 = ssrc[i + 1], e2 = ssrc[i + 2], e3 = ssrc[i + 3];
        a0 += in[(size_t)e0 * in_stride + f];
        a1 += in[(size_t)e1 * in_stride + f];
        a2 += in[(size_t)e2 * in_stride + f];
        a3 += in[(size_t)e3 * in_stride + f];
    }
    for (; i < s1; ++i) a0 += in[(size_t)ssrc[i] * in_stride + f];
    float acc = (a0 + a1) + (a2 + a3);
    int deg = s1 - s0;
    out[(size_t)n * out_stride + f] = (deg > 0) ? acc * (1.0f / deg) : 0.f;
}

// ---------------------------------------------------------------------------
// Fused GEMM.
// MODE 0: out[r][c] = relu( A[r,:]·W0[c,:] + X[r,:]·W1[c,:] + bias[c] ), F_out=256
// MODE 1: blockIdx.y selects weight (y=0 -> W0, y=1 -> W1); out[r][y*128+c] = A[r,:]·W[c,:]
// out row stride is always 256 floats.
// ---------------------------------------------------------------------------
template <int K, int MODE>
__global__ __launch_bounds__(256) void k_gemm(const float* __restrict__ A,
                                              const float* __restrict__ X,
                                              const float* __restrict__ W0,
                                              const float* __restrict__ W1,
                                              const float* __restrict__ bias,
                                              float* __restrict__ out, int N) {
    constexpr int BM = 64, BN = 128, BK = 32;
    constexpr int LDA = BM + 4;  // 68: k-row stride 272B (16B-aligned)
    constexpr int LDW = BN + 4;  // 132: 528B (16B-aligned)
    __shared__ alignas(16) float As[BK * LDA];
    __shared__ alignas(16) float Ws[BK * LDW];
    __shared__ alignas(16) float Xs[MODE == 0 ? BK * LDA : 1];
    __shared__ alignas(16) float Us[MODE == 0 ? BK * LDW : 1];

    const int tid = threadIdx.x;
    const int tx = tid & 15;   // 16 col-groups
    const int ty = tid >> 4;   // 16 row-groups
    const int row0 = blockIdx.x * BM;
    const int colb = blockIdx.y * BN;

    float acc[4][8];
#pragma unroll
    for (int i = 0; i < 4; ++i)
#pragma unroll
        for (int j = 0; j < 8; ++j) acc[i][j] = 0.f;

    const float* Wsrc = (MODE == 0) ? W0 : (blockIdx.y == 0 ? W0 : W1);

    for (int kk = 0; kk < K; kk += BK) {
        // stage A (and X) tiles, transposed: As[k][m]
#pragma unroll
        for (int rep = 0; rep < 2; ++rep) {
            int idx = rep * 256 + tid;
            int r = idx >> 3;
            int k4 = (idx & 7) << 2;
            int row = row0 + r;
            float4 va = make_float4(0.f, 0.f, 0.f, 0.f);
            if (row < N) va = *(const float4*)&A[(size_t)row * K + kk + k4];
            As[(k4 + 0) * LDA + r] = va.x;
            As[(k4 + 1) * LDA + r] = va.y;
            As[(k4 + 2) * LDA + r] = va.z;
            As[(k4 + 3) * LDA + r] = va.w;
            if constexpr (MODE == 0) {
                float4 vx = make_float4(0.f, 0.f, 0.f, 0.f);
                if (row < N) vx = *(const float4*)&X[(size_t)row * K + kk + k4];
                Xs[(k4 + 0) * LDA + r] = vx.x;
                Xs[(k4 + 1) * LDA + r] = vx.y;
                Xs[(k4 + 2) * LDA + r] = vx.z;
                Xs[(k4 + 3) * LDA + r] = vx.w;
            }
        }
        // stage W tiles, transposed: Ws[k][c]
#pragma unroll
        for (int rep = 0; rep < 4; ++rep) {
            int idx = rep * 256 + tid;
            int c = idx >> 3;  // 0..127
            int k4 = (idx & 7) << 2;
            int wrow = (MODE == 0) ? (colb + c) : c;
            float4 vw = *(const float4*)&Wsrc[(size_t)wrow * K + kk + k4];
            Ws[(k4 + 0) * LDW + c] = vw.x;
            Ws[(k4 + 1) * LDW + c] = vw.y;
            Ws[(k4 + 2) * LDW + c] = vw.z;
            Ws[(k4 + 3) * LDW + c] = vw.w;
            if constexpr (MODE == 0) {
                float4 vu = *(const float4*)&W1[(size_t)(colb + c) * K + kk + k4];
                Us[(k4 + 0) * LDW + c] = vu.x;
                Us[(k4 + 1) * LDW + c] = vu.y;
                Us[(k4 + 2) * LDW + c] = vu.z;
                Us[(k4 + 3) * LDW + c] = vu.w;
            }
        }
        __syncthreads();
#pragma unroll
        for (int k = 0; k < BK; ++k) {
            const float4 a4 = *(const float4*)&As[k * LDA + (ty << 2)];
            const float4 w04 = *(const float4*)&Ws[k * LDW + (tx << 2)];
            const float4 w14 = *(const float4*)&Ws[k * LDW + 64 + (tx << 2)];
            float av[4] = {a4.x, a4.y, a4.z, a4.w};
            float wv[8] = {w04.x, w04.y, w04.z, w04.w, w14.x, w14.y, w14.z, w14.w};
            if constexpr (MODE == 0) {
                const float4 x4 = *(const float4*)&Xs[k * LDA + (ty << 2)];
                const float4 u04 = *(const float4*)&Us[k * LDW + (tx << 2)];
                const float4 u14 = *(const float4*)&Us[k * LDW + 64 + (tx << 2)];
                float xv[4] = {x4.x, x4.y, x4.z, x4.w};
                float uv[8] = {u04.x, u04.y, u04.z, u04.w, u14.x, u14.y, u14.z, u14.w};
#pragma unroll
                for (int i = 0; i < 4; ++i)
#pragma unroll
                    for (int j = 0; j < 8; ++j)
                        acc[i][j] += av[i] * wv[j] + xv[i] * uv[j];
            } else {
#pragma unroll
                for (int i = 0; i < 4; ++i)
#pragma unroll
                    for (int j = 0; j < 8; ++j) acc[i][j] += av[i] * wv[j];
            }
        }
        __syncthreads();
    }

    // epilogue: float4 stores, out stride 256
#pragma unroll
    for (int i = 0; i < 4; ++i) {
        int r = row0 + (ty << 2) + i;
        if (r >= N) continue;
        size_t rb = (size_t)r * 256;
#pragma unroll
        for (int jh = 0; jh < 2; ++jh) {
            int c = colb + jh * 64 + (tx << 2);
            float4 v;
            float* vp = &v.x;
#pragma unroll
            for (int j = 0; j < 4; ++j) {
                float t = acc[i][jh * 4 + j];
                if constexpr (MODE == 0) {
                    t += bias[c + j];
                    t = fmaxf(t, 0.f);
                }
                vp[j] = t;
            }
            *(float4*)&out[rb + c] = v;
        }
    }
}

// ---------------------------------------------------------------------------
// Final: h3 = relu(agg3 + b3 + t3r), then pooled sum per graph (batch sorted ->
// run-length local accumulation, one atomic per run per thread).
// ---------------------------------------------------------------------------
__global__ __launch_bounds__(256) void k_final(const float* __restrict__ agg3,
                                               const float* __restrict__ t3,
                                               const float* __restrict__ b3,
                                               const int* __restrict__ batch,
                                               float* __restrict__ out) {
    const int f = threadIdx.x & 127;
    const int sub = threadIdx.x >> 7;  // 0 or 1
    const int n0 = blockIdx.x * 64;
    const int nend = min(n0 + 64, N_NODES);
    float local = 0.f;
    int cur = -1;
    float bf = b3[f];
    for (int n = n0 + sub; n < nend; n += 2) {
        float v = agg3[(size_t)n * 128 + f] + bf + t3[(size_t)n * 256 + 128 + f];
        v = fmaxf(v, 0.f);
        int b = batch[n];
        if (b != cur) {
            if (cur >= 0) atomicAdd(&out[(size_t)cur * 128 + f], local);
            local = 0.f;
            cur = b;
        }
        local += v;
    }
    if (cur >= 0) atomicAdd(&out[(size_t)cur * 128 + f], local);
}

// ---------------------------------------------------------------------------
extern "C" void kernel_launch(void* const* d_in, const int* in_sizes, int n_in,
                              void* d_out, int out_size, void* d_ws, size_t ws_size,
                              hipStream_t stream) {
    const float* x   = (const float*)d_in[0];
    const int* ei    = (const int*)d_in[1];
    const int* batch = (const int*)d_in[2];
    const float* W1l = (const float*)d_in[3];
    const float* b1  = (const float*)d_in[4];
    const float* W1r = (const float*)d_in[5];
    const float* W2l = (const float*)d_in[6];
    const float* b2  = (const float*)d_in[7];
    const float* W2r = (const float*)d_in[8];
    const float* W3l = (const float*)d_in[9];
    const float* b3  = (const float*)d_in[10];
    const float* W3r = (const float*)d_in[11];
    const int* src = ei;
    const int* dst = ei + N_EDGES;
    float* out = (float*)d_out;

    // workspace carve (256B aligned)
    size_t off = 0;
    auto carve = [&](size_t bytes) {
        void* p = (char*)d_ws + off;
        off += (bytes + 255) & ~(size_t)255;
        return p;
    };
    int* counts  = (int*)carve((size_t)N_NODES * 4);
    int* offs    = (int*)carve((size_t)(N_NODES + 1) * 4);
    int* ssrc    = (int*)carve((size_t)N_EDGES * 4);
    float* agg   = (float*)carve((size_t)N_NODES * 256 * 4);  // agg1/agg2/agg3
    float* h1t3  = (float*)carve((size_t)N_NODES * 256 * 4);  // h1, then t3
    float* h2    = (float*)carve((size_t)N_NODES * 256 * 4);

    hipMemsetAsync(counts, 0, (size_t)N_NODES * 4, stream);
    hipMemsetAsync(d_out, 0, (size_t)out_size * 4, stream);

    const int EB = (N_EDGES + 255) / 256;
    k_hist<<<EB, 256, 0, stream>>>(dst, counts);
    k_scan<<<1, 1024, 0, stream>>>(counts, offs);
    k_fill<<<EB, 256, 0, stream>>>(src, dst, offs, counts, ssrc);

    const dim3 gemm_grid((N_NODES + 63) / 64, 2);

    // Layer 1: agg1 = mean(x[src]) [128]; h1 = relu(agg1@W1l^T + b1 + x@W1r^T)
    k_gather<128><<<(N_NODES + 1) / 2, 256, 0, stream>>>(x, 128, agg, 128, offs, ssrc);
    k_gemm<128, 0><<<gemm_grid, 256, 0, stream>>>(agg, x, W1l, W1r, b1, h1t3, N_NODES);

    // Layer 2: agg2 = mean(h1[src]) [256]; h2 = relu(agg2@W2l^T + b2 + h1@W2r^T)
    k_gather<256><<<N_NODES, 256, 0, stream>>>(h1t3, 256, agg, 256, offs, ssrc);
    k_gemm<256, 0><<<gemm_grid, 256, 0, stream>>>(agg, h1t3, W2l, W2r, b2, h2, N_NODES);

    // Layer 3 (transform first): t3 = [h2@W3l^T | h2@W3r^T]  [N][256]
    k_gemm<256, 1><<<gemm_grid, 256, 0, stream>>>(h2, h2, W3l, W3r, nullptr, h1t3, N_NODES);
    // agg3 = mean(t3l[src]) [128]
    k_gather<128><<<(N_NODES + 1) / 2, 256, 0, stream>>>(h1t3, 256, agg, 128, offs, ssrc);
    // h3 = relu(agg3 + b3 + t3r); out[g] += h3
    k_final<<<(N_NODES + 63) / 64, 256, 0, stream>>>(agg, h1t3, b3, batch, out);
}

// Round 3
// 705.364 us; speedup vs baseline: 2.4122x; 2.4122x over previous
//
#include <hip/hip_runtime.h>
#include <hip/hip_bf16.h>

#define N_NODES 50000
#define N_EDGES 1600000
#define N_GRAPHS 64

typedef short bf16x8 __attribute__((ext_vector_type(8)));
typedef float f32x4 __attribute__((ext_vector_type(4)));

__device__ __forceinline__ float bf_lo(unsigned int u) { return __uint_as_float(u << 16); }
__device__ __forceinline__ float bf_hi(unsigned int u) { return __uint_as_float(u & 0xffff0000u); }
__device__ __forceinline__ unsigned short f2bf(float f) {
    unsigned int u = __float_as_uint(f);
    u = (u + 0x7fffu + ((u >> 16) & 1u)) >> 16;
    return (unsigned short)u;
}
__device__ __forceinline__ unsigned int pack2bf(float a, float b) {
    return (unsigned int)f2bf(a) | ((unsigned int)f2bf(b) << 16);
}
__device__ __forceinline__ void load_lds16(const void* g, void* l) {
    __builtin_amdgcn_global_load_lds(
        (const __attribute__((address_space(1))) void*)g,
        (__attribute__((address_space(3))) void*)l, 16, 0, 0);
}

// ---------------------------------------------------------------------------
// CSR build: histogram -> single-block scan -> fill
// ---------------------------------------------------------------------------
__global__ void k_hist(const int* __restrict__ dst, int* __restrict__ counts) {
    int e = blockIdx.x * blockDim.x + threadIdx.x;
    if (e < N_EDGES) atomicAdd(&counts[dst[e]], 1);
}

__global__ void k_scan(int* __restrict__ counts, int* __restrict__ offs) {
    __shared__ int lds[1024];
    const int t = threadIdx.x;
    const int CHUNK = 49;
    int base = t * CHUNK;
    int end = min(base + CHUNK, N_NODES);
    int s = 0;
    for (int i = base; i < end; ++i) s += counts[i];
    lds[t] = s;
    __syncthreads();
    for (int off = 1; off < 1024; off <<= 1) {
        int v = (t >= off) ? lds[t - off] : 0;
        __syncthreads();
        lds[t] += v;
        __syncthreads();
    }
    int run = lds[t] - s;
    for (int i = base; i < end; ++i) {
        offs[i] = run;
        run += counts[i];
        counts[i] = 0;  // reset: reused as cursor in k_fill
    }
    if (t == 1023) offs[N_NODES] = lds[1023];
}

__global__ void k_fill(const int* __restrict__ src, const int* __restrict__ dst,
                       const int* __restrict__ offs, int* __restrict__ cursor,
                       int* __restrict__ ssrc) {
    int e = blockIdx.x * blockDim.x + threadIdx.x;
    if (e < N_EDGES) {
        int d = dst[e];
        int p = offs[d] + atomicAdd(&cursor[d], 1);
        ssrc[p] = src[e];
    }
}

// ---------------------------------------------------------------------------
// Strided f32 -> bf16 convert (4 elems/thread). SF = source row width.
// ---------------------------------------------------------------------------
template <int SF>
__global__ __launch_bounds__(256) void k_cvt(const float* __restrict__ src,
                                             unsigned short* __restrict__ dst,
                                             int dstride, int total4) {
    int i = blockIdx.x * 256 + threadIdx.x;
    if (i >= total4) return;
    int r = i / (SF / 4);
    int f4 = (i % (SF / 4)) * 4;
    float4 v = *(const float4*)&src[(size_t)r * SF + f4];
    uint2 o;
    o.x = pack2bf(v.x, v.y);
    o.y = pack2bf(v.z, v.w);
    *(uint2*)&dst[(size_t)r * dstride + f4] = o;
}

// ---------------------------------------------------------------------------
// Gather-mean in bf16 (fp32 accumulate). Each thread: 4 features (uint2 load).
// ---------------------------------------------------------------------------
template <int F>
__global__ __launch_bounds__(256) void k_gather_bf(const unsigned short* __restrict__ in,
                                                   int istride,
                                                   unsigned short* __restrict__ out,
                                                   int ostride,
                                                   const int* __restrict__ offs,
                                                   const int* __restrict__ ssrc) {
    constexpr int TPN = F / 4;
    constexpr int NPB = 256 / TPN;
    int n = blockIdx.x * NPB + threadIdx.x / TPN;
    int f4 = (threadIdx.x % TPN) * 4;
    if (n >= N_NODES) return;
    int s0 = offs[n], s1 = offs[n + 1];
    float a0 = 0.f, a1 = 0.f, a2 = 0.f, a3 = 0.f;
    int i = s0;
    for (; i + 2 <= s1; i += 2) {
        int e0 = ssrc[i], e1 = ssrc[i + 1];
        uint2 v0 = *(const uint2*)&in[(size_t)e0 * istride + f4];
        uint2 v1 = *(const uint2*)&in[(size_t)e1 * istride + f4];
        a0 += bf_lo(v0.x) + bf_lo(v1.x);
        a1 += bf_hi(v0.x) + bf_hi(v1.x);
        a2 += bf_lo(v0.y) + bf_lo(v1.y);
        a3 += bf_hi(v0.y) + bf_hi(v1.y);
    }
    if (i < s1) {
        uint2 v0 = *(const uint2*)&in[(size_t)ssrc[i] * istride + f4];
        a0 += bf_lo(v0.x);
        a1 += bf_hi(v0.x);
        a2 += bf_lo(v0.y);
        a3 += bf_hi(v0.y);
    }
    int deg = s1 - s0;
    float sc = (deg > 0) ? 1.f / (float)deg : 0.f;
    uint2 o;
    o.x = pack2bf(a0 * sc, a1 * sc);
    o.y = pack2bf(a2 * sc, a3 * sc);
    *(uint2*)&out[(size_t)n * ostride + f4] = o;
}

// ---------------------------------------------------------------------------
// bf16 MFMA GEMM: C[m][coff+n] = op( A[m,:] . W[n,:] + bias[n] )
// A: [M][K] bf16 (row stride K), W: [256][K] bf16, output bf16 (row stride ldc).
// 128x128 tile, 4 waves (each 64x64), BK=64, global_load_lds staging with
// XOR-swizzle (slot ^= row&7; inverse-swizzled global source, swizzled read).
// ---------------------------------------------------------------------------
template <int KSTEPS, bool RELU, bool BIAS>
__global__ __launch_bounds__(256) void k_gemm_mfma(const unsigned short* __restrict__ A,
                                                   const unsigned short* __restrict__ W,
                                                   const float* __restrict__ bias,
                                                   unsigned short* __restrict__ C,
                                                   int ldc, int coff, int M) {
    constexpr int K = KSTEPS * 64;
    __shared__ unsigned short As[128 * 64];
    __shared__ unsigned short Ws[128 * 64];

    const int tid = threadIdx.x;
    const int lane = tid & 63;
    const int w = tid >> 6;  // wave 0..3
    const int row0 = blockIdx.x * 128;
    const int colb = blockIdx.y * 128;

    // staging geometry: per wave-iteration, 64 lanes write 1KB linear LDS
    const int srow_b = w * 32 + (lane >> 3);  // + it*8
    const int slot = lane & 7;

    f32x4 acc[4][4];
#pragma unroll
    for (int i = 0; i < 4; ++i)
#pragma unroll
        for (int j = 0; j < 4; ++j) acc[i][j] = (f32x4){0.f, 0.f, 0.f, 0.f};

    const int m0 = (w >> 1) * 64;
    const int n0 = (w & 1) * 64;

    for (int ks = 0; ks < KSTEPS; ++ks) {
        const int kk0 = ks * 64;
#pragma unroll
        for (int it = 0; it < 4; ++it) {
            int r = srow_b + it * 8;
            int sl = (slot ^ (r & 7)) << 3;  // inverse-swizzled source k-offset (elems)
            int ra = min(row0 + r, M - 1);
            load_lds16(A + (size_t)ra * K + kk0 + sl,
                       (char*)As + w * 4096 + it * 1024);
            load_lds16(W + (size_t)(colb + r) * K + kk0 + sl,
                       (char*)Ws + w * 4096 + it * 1024);
        }
        __syncthreads();

        bf16x8 af[4][2], bf[4][2];
#pragma unroll
        for (int mf = 0; mf < 4; ++mf)
#pragma unroll
            for (int kk = 0; kk < 2; ++kk) {
                int r = m0 + mf * 16 + (lane & 15);
                int sl = (kk * 4 + (lane >> 4)) ^ (r & 7);
                af[mf][kk] = *(const bf16x8*)((const char*)As + r * 128 + sl * 16);
            }
#pragma unroll
        for (int nf = 0; nf < 4; ++nf)
#pragma unroll
            for (int kk = 0; kk < 2; ++kk) {
                int r = n0 + nf * 16 + (lane & 15);
                int sl = (kk * 4 + (lane >> 4)) ^ (r & 7);
                bf[nf][kk] = *(const bf16x8*)((const char*)Ws + r * 128 + sl * 16);
            }
#pragma unroll
        for (int mf = 0; mf < 4; ++mf)
#pragma unroll
            for (int nf = 0; nf < 4; ++nf)
#pragma unroll
                for (int kk = 0; kk < 2; ++kk)
                    acc[mf][nf] = __builtin_amdgcn_mfma_f32_16x16x32_bf16(
                        af[mf][kk], bf[nf][kk], acc[mf][nf], 0, 0, 0);
        __syncthreads();
    }

    // epilogue: C/D layout col=lane&15, row=(lane>>4)*4+reg
#pragma unroll
    for (int mf = 0; mf < 4; ++mf) {
#pragma unroll
        for (int nf = 0; nf < 4; ++nf) {
            int c = colb + n0 + nf * 16 + (lane & 15);
            float bv = 0.f;
            if constexpr (BIAS) bv = bias[c];
#pragma unroll
            for (int r = 0; r < 4; ++r) {
                int m = row0 + m0 + mf * 16 + ((lane >> 4) << 2) + r;
                if (m < M) {
                    float v = acc[mf][nf][r] + bv;
                    if constexpr (RELU) v = fmaxf(v, 0.f);
                    C[(size_t)m * ldc + coff + c] = f2bf(v);
                }
            }
        }
    }
}

// ---------------------------------------------------------------------------
// Final: h3 = relu(agg3 + b3 + t3r), pooled per-graph sum (batch sorted).
// ---------------------------------------------------------------------------
__global__ __launch_bounds__(256) void k_final(const unsigned short* __restrict__ agg3,
                                               const unsigned short* __restrict__ t3,
                                               const float* __restrict__ b3,
                                               const int* __restrict__ batch,
                                               float* __restrict__ out) {
    const int f = threadIdx.x & 127;
    const int sub = threadIdx.x >> 7;
    const int n0 = blockIdx.x * 64;
    const int nend = min(n0 + 64, N_NODES);
    float local = 0.f;
    int cur = -1;
    float bfv = b3[f];
    for (int n = n0 + sub; n < nend; n += 2) {
        float v = __uint_as_float(((unsigned int)agg3[(size_t)n * 128 + f]) << 16) + bfv +
                  __uint_as_float(((unsigned int)t3[(size_t)n * 256 + 128 + f]) << 16);
        v = fmaxf(v, 0.f);
        int b = batch[n];
        if (b != cur) {
            if (cur >= 0) atomicAdd(&out[(size_t)cur * 128 + f], local);
            local = 0.f;
            cur = b;
        }
        local += v;
    }
    if (cur >= 0) atomicAdd(&out[(size_t)cur * 128 + f], local);
}

// ---------------------------------------------------------------------------
extern "C" void kernel_launch(void* const* d_in, const int* in_sizes, int n_in,
                              void* d_out, int out_size, void* d_ws, size_t ws_size,
                              hipStream_t stream) {
    const float* x   = (const float*)d_in[0];
    const int* ei    = (const int*)d_in[1];
    const int* batch = (const int*)d_in[2];
    const float* W1l = (const float*)d_in[3];
    const float* b1  = (const float*)d_in[4];
    const float* W1r = (const float*)d_in[5];
    const float* W2l = (const float*)d_in[6];
    const float* b2  = (const float*)d_in[7];
    const float* W2r = (const float*)d_in[8];
    const float* W3l = (const float*)d_in[9];
    const float* b3  = (const float*)d_in[10];
    const float* W3r = (const float*)d_in[11];
    const int* src = ei;
    const int* dst = ei + N_EDGES;
    float* out = (float*)d_out;

    size_t off = 0;
    auto carve = [&](size_t bytes) {
        void* p = (char*)d_ws + off;
        off += (bytes + 255) & ~(size_t)255;
        return p;
    };
    int* counts = (int*)carve((size_t)N_NODES * 4);
    int* offs   = (int*)carve((size_t)(N_NODES + 1) * 4);
    int* ssrc   = (int*)carve((size_t)N_EDGES * 4);
    unsigned short* A1   = (unsigned short*)carve((size_t)N_NODES * 256 * 2);  // [agg1|x]
    unsigned short* A2   = (unsigned short*)carve((size_t)N_NODES * 512 * 2);  // [agg2|h1]
    unsigned short* A3   = (unsigned short*)carve((size_t)N_NODES * 256 * 2);  // h2
    unsigned short* t3   = (unsigned short*)carve((size_t)N_NODES * 256 * 2);  // [t3l|t3r]
    unsigned short* agg3 = (unsigned short*)carve((size_t)N_NODES * 128 * 2);
    unsigned short* Wp1  = (unsigned short*)carve((size_t)256 * 256 * 2);
    unsigned short* Wp2  = (unsigned short*)carve((size_t)256 * 512 * 2);
    unsigned short* Wp3  = (unsigned short*)carve((size_t)256 * 256 * 2);

    hipMemsetAsync(counts, 0, (size_t)N_NODES * 4, stream);
    hipMemsetAsync(d_out, 0, (size_t)out_size * 4, stream);

    const int EB = (N_EDGES + 255) / 256;
    k_hist<<<EB, 256, 0, stream>>>(dst, counts);
    k_scan<<<1, 1024, 0, stream>>>(counts, offs);
    k_fill<<<EB, 256, 0, stream>>>(src, dst, offs, counts, ssrc);

    // converts: x -> A1 right half; weights -> packed bf16
    k_cvt<128><<<(50000 * 32 + 255) / 256, 256, 0, stream>>>(x, A1 + 128, 256, 50000 * 32);
    k_cvt<128><<<32, 256, 0, stream>>>(W1l, Wp1, 256, 256 * 32);
    k_cvt<128><<<32, 256, 0, stream>>>(W1r, Wp1 + 128, 256, 256 * 32);
    k_cvt<256><<<64, 256, 0, stream>>>(W2l, Wp2, 512, 256 * 64);
    k_cvt<256><<<64, 256, 0, stream>>>(W2r, Wp2 + 256, 512, 256 * 64);
    k_cvt<256><<<32, 256, 0, stream>>>(W3l, Wp3, 256, 128 * 64);
    k_cvt<256><<<32, 256, 0, stream>>>(W3r, Wp3 + 128 * 256, 256, 128 * 64);

    const dim3 ggrid((N_NODES + 127) / 128, 2);

    // L1: agg1 = mean(x_bf[src]); h1 = relu([agg1|x] @ Wp1^T + b1) -> A2 cols 256..511
    k_gather_bf<128><<<N_NODES / 8, 256, 0, stream>>>(A1 + 128, 256, A1, 256, offs, ssrc);
    k_gemm_mfma<4, true, true><<<ggrid, 256, 0, stream>>>(A1, Wp1, b1, A2, 512, 256, N_NODES);

    // L2: agg2 = mean(h1[src]); h2 = relu([agg2|h1] @ Wp2^T + b2) -> A3
    k_gather_bf<256><<<N_NODES / 4, 256, 0, stream>>>(A2 + 256, 512, A2, 512, offs, ssrc);
    k_gemm_mfma<8, true, true><<<ggrid, 256, 0, stream>>>(A2, Wp2, b2, A3, 256, 0, N_NODES);

    // L3: t3 = h2 @ [W3l;W3r]^T ; agg3 = mean(t3l[src]); h3 = relu(agg3+b3+t3r); pool
    k_gemm_mfma<4, false, false><<<ggrid, 256, 0, stream>>>(A3, Wp3, nullptr, t3, 256, 0, N_NODES);
    k_gather_bf<128><<<N_NODES / 8, 256, 0, stream>>>(t3, 256, agg3, 128, offs, ssrc);
    k_final<<<(N_NODES + 63) / 64, 256, 0, stream>>>(agg3, t3, b3, batch, out);
}

// Round 4
// 672.964 us; speedup vs baseline: 2.5283x; 1.0481x over previous
//
#include <hip/hip_runtime.h>
#include <hip/hip_bf16.h>

#define N_NODES 50000
#define N_EDGES 1600000
#define N_GRAPHS 64

typedef short bf16x8 __attribute__((ext_vector_type(8)));
typedef float f32x4 __attribute__((ext_vector_type(4)));

__device__ __forceinline__ float bf_lo(unsigned int u) { return __uint_as_float(u << 16); }
__device__ __forceinline__ float bf_hi(unsigned int u) { return __uint_as_float(u & 0xffff0000u); }
__device__ __forceinline__ unsigned short f2bf(float f) {
    unsigned int u = __float_as_uint(f);
    u = (u + 0x7fffu + ((u >> 16) & 1u)) >> 16;
    return (unsigned short)u;
}
__device__ __forceinline__ unsigned int pack2bf(float a, float b) {
    return (unsigned int)f2bf(a) | ((unsigned int)f2bf(b) << 16);
}
__device__ __forceinline__ void load_lds16(const void* g, void* l) {
    __builtin_amdgcn_global_load_lds(
        (const __attribute__((address_space(1))) void*)g,
        (__attribute__((address_space(3))) void*)l, 16, 0, 0);
}

// ---------------------------------------------------------------------------
// CSR build: histogram -> single-block scan -> fill
// ---------------------------------------------------------------------------
__global__ void k_hist(const int* __restrict__ dst, int* __restrict__ counts) {
    int e = blockIdx.x * blockDim.x + threadIdx.x;
    if (e < N_EDGES) atomicAdd(&counts[dst[e]], 1);
}

__global__ void k_scan(int* __restrict__ counts, int* __restrict__ offs) {
    __shared__ int lds[1024];
    const int t = threadIdx.x;
    const int CHUNK = 49;
    int base = t * CHUNK;
    int end = min(base + CHUNK, N_NODES);
    int s = 0;
    for (int i = base; i < end; ++i) s += counts[i];
    lds[t] = s;
    __syncthreads();
    for (int off = 1; off < 1024; off <<= 1) {
        int v = (t >= off) ? lds[t - off] : 0;
        __syncthreads();
        lds[t] += v;
        __syncthreads();
    }
    int run = lds[t] - s;
    for (int i = base; i < end; ++i) {
        offs[i] = run;
        run += counts[i];
        counts[i] = 0;  // reset: reused as cursor in k_fill
    }
    if (t == 1023) offs[N_NODES] = lds[1023];
}

__global__ void k_fill(const int* __restrict__ src, const int* __restrict__ dst,
                       const int* __restrict__ offs, int* __restrict__ cursor,
                       int* __restrict__ ssrc) {
    int e = blockIdx.x * blockDim.x + threadIdx.x;
    if (e < N_EDGES) {
        int d = dst[e];
        int p = offs[d] + atomicAdd(&cursor[d], 1);
        ssrc[p] = src[e];
    }
}

// ---------------------------------------------------------------------------
// f32 -> bf16 converts
// ---------------------------------------------------------------------------
template <int SF>
__global__ __launch_bounds__(256) void k_cvt(const float* __restrict__ src,
                                             unsigned short* __restrict__ dst,
                                             int dstride, int total4) {
    int i = blockIdx.x * 256 + threadIdx.x;
    if (i >= total4) return;
    int r = i / (SF / 4);
    int f4 = (i % (SF / 4)) * 4;
    float4 v = *(const float4*)&src[(size_t)r * SF + f4];
    uint2 o;
    o.x = pack2bf(v.x, v.y);
    o.y = pack2bf(v.z, v.w);
    *(uint2*)&dst[(size_t)r * dstride + f4] = o;
}

// all 6 weight matrices in one launch (65536 float4-units, 256 blocks)
__global__ __launch_bounds__(256) void k_cvt_w(const float* __restrict__ W1l,
                                               const float* __restrict__ W1r,
                                               const float* __restrict__ W2l,
                                               const float* __restrict__ W2r,
                                               const float* __restrict__ W3l,
                                               const float* __restrict__ W3r,
                                               unsigned short* __restrict__ Wp1,
                                               unsigned short* __restrict__ Wp2,
                                               unsigned short* __restrict__ Wp3) {
    int i = blockIdx.x * 256 + threadIdx.x;  // 0..65535
    const float* src;
    unsigned short* dst;
    int sf4, dstride;
    if (i < 16384) {  // W1l/W1r: [256][128], 8192 units each
        int h = i >> 13;
        i &= 8191;
        src = h ? W1r : W1l;
        dst = Wp1 + (h ? 128 : 0);
        sf4 = 32; dstride = 256;
    } else if (i < 49152) {  // W2l/W2r: [256][256], 16384 units each
        int j = i - 16384;
        int h = j >> 14;
        i = j & 16383;
        src = h ? W2r : W2l;
        dst = Wp2 + (h ? 256 : 0);
        sf4 = 64; dstride = 512;
    } else {  // W3l/W3r: [128][256], 8192 units each
        int j = i - 49152;
        int h = j >> 13;
        i = j & 8191;
        src = h ? W3r : W3l;
        dst = Wp3 + (h ? 128 * 256 : 0);
        sf4 = 64; dstride = 256;
    }
    int r = i / sf4;
    int f4 = (i % sf4) * 4;
    float4 v = *(const float4*)&src[(size_t)r * (sf4 * 4) + f4];
    uint2 o;
    o.x = pack2bf(v.x, v.y);
    o.y = pack2bf(v.z, v.w);
    *(uint2*)&dst[(size_t)r * dstride + f4] = o;
}

// ---------------------------------------------------------------------------
// Gather-mean in bf16 (fp32 accumulate). 8 feats/thread (uint4), 4-edge unroll
// -> 64B in flight per thread.
// ---------------------------------------------------------------------------
template <int F>
__global__ __launch_bounds__(256) void k_gather_bf(const unsigned short* __restrict__ in,
                                                   int istride,
                                                   unsigned short* __restrict__ out,
                                                   int ostride,
                                                   const int* __restrict__ offs,
                                                   const int* __restrict__ ssrc) {
    constexpr int TPN = F / 8;
    constexpr int NPB = 256 / TPN;
    int n = blockIdx.x * NPB + threadIdx.x / TPN;
    int f8 = (threadIdx.x % TPN) * 8;
    if (n >= N_NODES) return;
    int s0 = offs[n], s1 = offs[n + 1];
    float a0 = 0.f, a1 = 0.f, a2 = 0.f, a3 = 0.f;
    float a4 = 0.f, a5 = 0.f, a6 = 0.f, a7 = 0.f;
    const unsigned short* inf = in + f8;
    int i = s0;
    for (; i + 4 <= s1; i += 4) {
        int e0 = ssrc[i], e1 = ssrc[i + 1], e2 = ssrc[i + 2], e3 = ssrc[i + 3];
        uint4 v0 = *(const uint4*)&inf[(size_t)e0 * istride];
        uint4 v1 = *(const uint4*)&inf[(size_t)e1 * istride];
        uint4 v2 = *(const uint4*)&inf[(size_t)e2 * istride];
        uint4 v3 = *(const uint4*)&inf[(size_t)e3 * istride];
        a0 += (bf_lo(v0.x) + bf_lo(v1.x)) + (bf_lo(v2.x) + bf_lo(v3.x));
        a1 += (bf_hi(v0.x) + bf_hi(v1.x)) + (bf_hi(v2.x) + bf_hi(v3.x));
        a2 += (bf_lo(v0.y) + bf_lo(v1.y)) + (bf_lo(v2.y) + bf_lo(v3.y));
        a3 += (bf_hi(v0.y) + bf_hi(v1.y)) + (bf_hi(v2.y) + bf_hi(v3.y));
        a4 += (bf_lo(v0.z) + bf_lo(v1.z)) + (bf_lo(v2.z) + bf_lo(v3.z));
        a5 += (bf_hi(v0.z) + bf_hi(v1.z)) + (bf_hi(v2.z) + bf_hi(v3.z));
        a6 += (bf_lo(v0.w) + bf_lo(v1.w)) + (bf_lo(v2.w) + bf_lo(v3.w));
        a7 += (bf_hi(v0.w) + bf_hi(v1.w)) + (bf_hi(v2.w) + bf_hi(v3.w));
    }
    for (; i < s1; ++i) {
        uint4 v = *(const uint4*)&inf[(size_t)ssrc[i] * istride];
        a0 += bf_lo(v.x); a1 += bf_hi(v.x);
        a2 += bf_lo(v.y); a3 += bf_hi(v.y);
        a4 += bf_lo(v.z); a5 += bf_hi(v.z);
        a6 += bf_lo(v.w); a7 += bf_hi(v.w);
    }
    int deg = s1 - s0;
    float sc = (deg > 0) ? 1.f / (float)deg : 0.f;
    uint4 o;
    o.x = pack2bf(a0 * sc, a1 * sc);
    o.y = pack2bf(a2 * sc, a3 * sc);
    o.z = pack2bf(a4 * sc, a5 * sc);
    o.w = pack2bf(a6 * sc, a7 * sc);
    *(uint4*)&out[(size_t)n * ostride + f8] = o;
}

// ---------------------------------------------------------------------------
// bf16 MFMA GEMM: C[m][coff+n] = op( A[m,:] . W[n,:] + bias[n] )
// 128x128 tile, 4 waves (64x64 each), BK=64, double-buffered LDS with 2-phase
// prefetch (stage t+1 before compute t; one barrier per K-step).
// XOR-swizzle both-sides: inverse-swizzled global source, swizzled ds_read.
// ---------------------------------------------------------------------------
template <int KSTEPS, bool RELU, bool BIAS>
__global__ __launch_bounds__(256) void k_gemm_mfma(const unsigned short* __restrict__ A,
                                                   const unsigned short* __restrict__ W,
                                                   const float* __restrict__ bias,
                                                   unsigned short* __restrict__ C,
                                                   int ldc, int coff, int M) {
    constexpr int K = KSTEPS * 64;
    __shared__ unsigned short As[2][128 * 64];
    __shared__ unsigned short Ws[2][128 * 64];

    const int tid = threadIdx.x;
    const int lane = tid & 63;
    const int w = tid >> 6;
    const int row0 = blockIdx.x * 128;
    const int colb = blockIdx.y * 128;

    const int srow_b = w * 32 + (lane >> 3);  // + it*8
    const int slot = lane & 7;

    f32x4 acc[4][4];
#pragma unroll
    for (int i = 0; i < 4; ++i)
#pragma unroll
        for (int j = 0; j < 4; ++j) acc[i][j] = (f32x4){0.f, 0.f, 0.f, 0.f};

    const int m0 = (w >> 1) * 64;
    const int n0 = (w & 1) * 64;

    auto STAGE = [&](int b, int ks) {
        const int kk0 = ks * 64;
#pragma unroll
        for (int it = 0; it < 4; ++it) {
            int r = srow_b + it * 8;
            int sl = (slot ^ (r & 7)) << 3;  // inverse-swizzled source k-offset
            int ra = min(row0 + r, M - 1);
            load_lds16(A + (size_t)ra * K + kk0 + sl,
                       (char*)As[b] + w * 4096 + it * 1024);
            load_lds16(W + (size_t)(colb + r) * K + kk0 + sl,
                       (char*)Ws[b] + w * 4096 + it * 1024);
        }
    };

    STAGE(0, 0);
    __syncthreads();
    int cur = 0;

    for (int ks = 0; ks < KSTEPS; ++ks) {
        if (ks + 1 < KSTEPS) STAGE(cur ^ 1, ks + 1);

        bf16x8 af[4][2], bfr[4][2];
#pragma unroll
        for (int mf = 0; mf < 4; ++mf)
#pragma unroll
            for (int kk = 0; kk < 2; ++kk) {
                int r = m0 + mf * 16 + (lane & 15);
                int sl = (kk * 4 + (lane >> 4)) ^ (r & 7);
                af[mf][kk] = *(const bf16x8*)((const char*)As[cur] + r * 128 + sl * 16);
            }
#pragma unroll
        for (int nf = 0; nf < 4; ++nf)
#pragma unroll
            for (int kk = 0; kk < 2; ++kk) {
                int r = n0 + nf * 16 + (lane & 15);
                int sl = (kk * 4 + (lane >> 4)) ^ (r & 7);
                bfr[nf][kk] = *(const bf16x8*)((const char*)Ws[cur] + r * 128 + sl * 16);
            }
#pragma unroll
        for (int mf = 0; mf < 4; ++mf)
#pragma unroll
            for (int nf = 0; nf < 4; ++nf)
#pragma unroll
                for (int kk = 0; kk < 2; ++kk)
                    acc[mf][nf] = __builtin_amdgcn_mfma_f32_16x16x32_bf16(
                        af[mf][kk], bfr[nf][kk], acc[mf][nf], 0, 0, 0);
        // drains this wave's STAGE loads (vmcnt) + syncs all waves before the
        // buffer we just staged is read / the one we read is overwritten
        __syncthreads();
        cur ^= 1;
    }

    // epilogue: C/D layout col=lane&15, row=(lane>>4)*4+reg
#pragma unroll
    for (int mf = 0; mf < 4; ++mf) {
#pragma unroll
        for (int nf = 0; nf < 4; ++nf) {
            int c = colb + n0 + nf * 16 + (lane & 15);
            float bv = 0.f;
            if constexpr (BIAS) bv = bias[c];
#pragma unroll
            for (int r = 0; r < 4; ++r) {
                int m = row0 + m0 + mf * 16 + ((lane >> 4) << 2) + r;
                if (m < M) {
                    float v = acc[mf][nf][r] + bv;
                    if constexpr (RELU) v = fmaxf(v, 0.f);
                    C[(size_t)m * ldc + coff + c] = f2bf(v);
                }
            }
        }
    }
}

// ---------------------------------------------------------------------------
// Final: h3 = relu(agg3 + b3 + t3r), pooled per-graph sum (batch sorted).
// ---------------------------------------------------------------------------
__global__ __launch_bounds__(256) void k_final(const unsigned short* __restrict__ agg3,
                                               const unsigned short* __restrict__ t3,
                                               const float* __restrict__ b3,
                                               const int* __restrict__ batch,
                                               float* __restrict__ out) {
    const int f = threadIdx.x & 127;
    const int sub = threadIdx.x >> 7;
    const int n0 = blockIdx.x * 64;
    const int nend = min(n0 + 64, N_NODES);
    float local = 0.f;
    int cur = -1;
    float bfv = b3[f];
    for (int n = n0 + sub; n < nend; n += 2) {
        float v = __uint_as_float(((unsigned int)agg3[(size_t)n * 128 + f]) << 16) + bfv +
                  __uint_as_float(((unsigned int)t3[(size_t)n * 256 + 128 + f]) << 16);
        v = fmaxf(v, 0.f);
        int b = batch[n];
        if (b != cur) {
            if (cur >= 0) atomicAdd(&out[(size_t)cur * 128 + f], local);
            local = 0.f;
            cur = b;
        }
        local += v;
    }
    if (cur >= 0) atomicAdd(&out[(size_t)cur * 128 + f], local);
}

// ---------------------------------------------------------------------------
extern "C" void kernel_launch(void* const* d_in, const int* in_sizes, int n_in,
                              void* d_out, int out_size, void* d_ws, size_t ws_size,
                              hipStream_t stream) {
    const float* x   = (const float*)d_in[0];
    const int* ei    = (const int*)d_in[1];
    const int* batch = (const int*)d_in[2];
    const float* W1l = (const float*)d_in[3];
    const float* b1  = (const float*)d_in[4];
    const float* W1r = (const float*)d_in[5];
    const float* W2l = (const float*)d_in[6];
    const float* b2  = (const float*)d_in[7];
    const float* W2r = (const float*)d_in[8];
    const float* W3l = (const float*)d_in[9];
    const float* b3  = (const float*)d_in[10];
    const float* W3r = (const float*)d_in[11];
    const int* src = ei;
    const int* dst = ei + N_EDGES;
    float* out = (float*)d_out;

    size_t off = 0;
    auto carve = [&](size_t bytes) {
        void* p = (char*)d_ws + off;
        off += (bytes + 255) & ~(size_t)255;
        return p;
    };
    int* counts = (int*)carve((size_t)N_NODES * 4);
    int* offs   = (int*)carve((size_t)(N_NODES + 1) * 4);
    int* ssrc   = (int*)carve((size_t)N_EDGES * 4);
    unsigned short* A1   = (unsigned short*)carve((size_t)N_NODES * 256 * 2);  // [agg1|x]
    unsigned short* A2   = (unsigned short*)carve((size_t)N_NODES * 512 * 2);  // [agg2|h1]
    unsigned short* A3   = (unsigned short*)carve((size_t)N_NODES * 256 * 2);  // h2
    unsigned short* t3   = (unsigned short*)carve((size_t)N_NODES * 256 * 2);  // [t3l|t3r]
    unsigned short* agg3 = (unsigned short*)carve((size_t)N_NODES * 128 * 2);
    unsigned short* Wp1  = (unsigned short*)carve((size_t)256 * 256 * 2);
    unsigned short* Wp2  = (unsigned short*)carve((size_t)256 * 512 * 2);
    unsigned short* Wp3  = (unsigned short*)carve((size_t)256 * 256 * 2);

    hipMemsetAsync(counts, 0, (size_t)N_NODES * 4, stream);
    hipMemsetAsync(d_out, 0, (size_t)out_size * 4, stream);

    const int EB = (N_EDGES + 255) / 256;
    k_hist<<<EB, 256, 0, stream>>>(dst, counts);
    k_scan<<<1, 1024, 0, stream>>>(counts, offs);
    k_fill<<<EB, 256, 0, stream>>>(src, dst, offs, counts, ssrc);

    // converts: x -> A1 right half; all 6 weights in one launch
    k_cvt<128><<<(50000 * 32 + 255) / 256, 256, 0, stream>>>(x, A1 + 128, 256, 50000 * 32);
    k_cvt_w<<<256, 256, 0, stream>>>(W1l, W1r, W2l, W2r, W3l, W3r, Wp1, Wp2, Wp3);

    const dim3 ggrid((N_NODES + 127) / 128, 2);

    // L1: agg1 = mean(x_bf[src]); h1 = relu([agg1|x] @ Wp1^T + b1) -> A2 cols 256..511
    k_gather_bf<128><<<(N_NODES + 15) / 16, 256, 0, stream>>>(A1 + 128, 256, A1, 256, offs, ssrc);
    k_gemm_mfma<4, true, true><<<ggrid, 256, 0, stream>>>(A1, Wp1, b1, A2, 512, 256, N_NODES);

    // L2: agg2 = mean(h1[src]); h2 = relu([agg2|h1] @ Wp2^T + b2) -> A3
    k_gather_bf<256><<<(N_NODES + 7) / 8, 256, 0, stream>>>(A2 + 256, 512, A2, 512, offs, ssrc);
    k_gemm_mfma<8, true, true><<<ggrid, 256, 0, stream>>>(A2, Wp2, b2, A3, 256, 0, N_NODES);

    // L3: t3 = h2 @ [W3l;W3r]^T ; agg3 = mean(t3l[src]); h3 = relu(agg3+b3+t3r); pool
    k_gemm_mfma<4, false, false><<<ggrid, 256, 0, stream>>>(A3, Wp3, nullptr, t3, 256, 0, N_NODES);
    k_gather_bf<128><<<(N_NODES + 15) / 16, 256, 0, stream>>>(t3, 256, agg3, 128, offs, ssrc);
    k_final<<<(N_NODES + 63) / 64, 256, 0, stream>>>(agg3, t3, b3, batch, out);
}

// Round 5
// 429.313 us; speedup vs baseline: 3.9632x; 1.5675x over previous
//
#include <hip/hip_runtime.h>
#include <hip/hip_bf16.h>

#define N_NODES 50000
#define N_EDGES 1600000
#define N_GRAPHS 64

// bucket sort geometry
#define NBKT 250          // buckets of 200 nodes each (250*200 = 50000)
#define BKT_NODES 200
#define BKT_CAP 7168      // >=22 sigma above mean 6400; guard-checked
#define CHUNK 2048        // edges per k_front bucket block
#define NBB 782           // ceil(1600000/2048)
#define NCVX 6250         // x-convert blocks (50000*128/4 units / 256)
#define NCVW 256          // weight-convert blocks

typedef short bf16x8 __attribute__((ext_vector_type(8)));
typedef float f32x4 __attribute__((ext_vector_type(4)));

__device__ __forceinline__ float bf_lo(unsigned int u) { return __uint_as_float(u << 16); }
__device__ __forceinline__ float bf_hi(unsigned int u) { return __uint_as_float(u & 0xffff0000u); }
__device__ __forceinline__ unsigned short f2bf(float f) {
    unsigned int u = __float_as_uint(f);
    u = (u + 0x7fffu + ((u >> 16) & 1u)) >> 16;
    return (unsigned short)u;
}
__device__ __forceinline__ unsigned int pack2bf(float a, float b) {
    return (unsigned int)f2bf(a) | ((unsigned int)f2bf(b) << 16);
}
__device__ __forceinline__ void load_lds16(const void* g, void* l) {
    __builtin_amdgcn_global_load_lds(
        (const __attribute__((address_space(1))) void*)g,
        (__attribute__((address_space(3))) void*)l, 16, 0, 0);
}

// ---------------------------------------------------------------------------
// k_front: fused {edge bucketing | x->bf16 convert | weight converts}
// Bucket blocks: LDS counting-sort of a 2048-edge chunk by coarse dst-bucket,
// then coalesced append to per-bucket global regions. packed entry:
// src(16b) | dst_local(8b) | bucket(8b).
// ---------------------------------------------------------------------------
__global__ __launch_bounds__(256) void k_front(
    const int* __restrict__ src, const int* __restrict__ dst,
    unsigned int* __restrict__ bucketed, int* __restrict__ gcnt,
    const float* __restrict__ x, unsigned short* __restrict__ A1x,
    const float* __restrict__ W1l, const float* __restrict__ W1r,
    const float* __restrict__ W2l, const float* __restrict__ W2r,
    const float* __restrict__ W3l, const float* __restrict__ W3r,
    unsigned short* __restrict__ Wp1, unsigned short* __restrict__ Wp2,
    unsigned short* __restrict__ Wp3) {
    const int blk = blockIdx.x;
    const int t = threadIdx.x;

    if (blk < NBB) {
        // ---- bucket section ----
        __shared__ int lcnt[256];
        __shared__ int sc[256];
        __shared__ int lscan[256];  // exclusive scan of lcnt
        __shared__ int gb[256];     // global base per bucket for this chunk
        __shared__ unsigned int grouped[CHUNK];

        const int base = blk * CHUNK;
        const int ccnt = min(CHUNK, N_EDGES - base);
        lcnt[t] = 0;
        __syncthreads();

        unsigned int pk[CHUNK / 256];
        int rk[CHUNK / 256];
#pragma unroll
        for (int r = 0; r < CHUNK / 256; ++r) {
            int j = r * 256 + t;
            rk[r] = -1;
            if (j < ccnt) {
                int i = base + j;
                int s = src[i];
                int d = dst[i];
                int b = d / BKT_NODES;
                int dl = d - b * BKT_NODES;
                pk[r] = (unsigned int)s | ((unsigned int)dl << 16) | ((unsigned int)b << 24);
                rk[r] = atomicAdd(&lcnt[b], 1);
            }
        }
        __syncthreads();
        // exclusive scan of lcnt -> lscan
        sc[t] = lcnt[t];
        __syncthreads();
        for (int off = 1; off < 256; off <<= 1) {
            int v = (t >= off) ? sc[t - off] : 0;
            __syncthreads();
            sc[t] += v;
            __syncthreads();
        }
        lscan[t] = sc[t] - lcnt[t];
        if (t < NBKT && lcnt[t] > 0) gb[t] = atomicAdd(&gcnt[t], lcnt[t]);
        __syncthreads();
        // group in LDS
#pragma unroll
        for (int r = 0; r < CHUNK / 256; ++r) {
            if (rk[r] >= 0) {
                int b = pk[r] >> 24;
                grouped[lscan[b] + rk[r]] = pk[r];
            }
        }
        __syncthreads();
        // coalesced-ish copy to global bucket regions
#pragma unroll
        for (int r = 0; r < CHUNK / 256; ++r) {
            int j = r * 256 + t;
            if (j < ccnt) {
                unsigned int v = grouped[j];
                int b = v >> 24;
                int pos = gb[b] + (j - lscan[b]);
                if (pos < BKT_CAP) bucketed[b * BKT_CAP + pos] = v;
            }
        }
    } else if (blk < NBB + NCVX) {
        // ---- x -> bf16 into A1 right half (row stride 256) ----
        int i = (blk - NBB) * 256 + t;  // unit = 4 floats; exactly 1.6M units
        int r = i >> 5;                  // /32
        int f4 = (i & 31) << 2;
        float4 v = *(const float4*)&x[(size_t)r * 128 + f4];
        uint2 o;
        o.x = pack2bf(v.x, v.y);
        o.y = pack2bf(v.z, v.w);
        *(uint2*)&A1x[(size_t)r * 256 + f4] = o;
    } else {
        // ---- all 6 weight matrices ----
        int i = (blk - NBB - NCVX) * 256 + t;  // 0..65535
        const float* srcp;
        unsigned short* dstp;
        int sf4, dstride;
        if (i < 16384) {
            int h = i >> 13;
            i &= 8191;
            srcp = h ? W1r : W1l;
            dstp = Wp1 + (h ? 128 : 0);
            sf4 = 32; dstride = 256;
        } else if (i < 49152) {
            int j = i - 16384;
            int h = j >> 14;
            i = j & 16383;
            srcp = h ? W2r : W2l;
            dstp = Wp2 + (h ? 256 : 0);
            sf4 = 64; dstride = 512;
        } else {
            int j = i - 49152;
            int h = j >> 13;
            i = j & 8191;
            srcp = h ? W3r : W3l;
            dstp = Wp3 + (h ? 128 * 256 : 0);
            sf4 = 64; dstride = 256;
        }
        int r = i / sf4;
        int f4 = (i % sf4) * 4;
        float4 v = *(const float4*)&srcp[(size_t)r * (sf4 * 4) + f4];
        uint2 o;
        o.x = pack2bf(v.x, v.y);
        o.y = pack2bf(v.z, v.w);
        *(uint2*)&dstp[(size_t)r * dstride + f4] = o;
    }
}

// ---------------------------------------------------------------------------
// k_bscan: exclusive scan of 250 bucket counts -> bstart; offs[N] = N_EDGES.
// ---------------------------------------------------------------------------
__global__ void k_bscan(const int* __restrict__ gcnt, int* __restrict__ bstart,
                        int* __restrict__ offs) {
    __shared__ int sc[256];
    const int t = threadIdx.x;
    int v = (t < NBKT) ? gcnt[t] : 0;
    sc[t] = v;
    __syncthreads();
    for (int off = 1; off < 256; off <<= 1) {
        int u = (t >= off) ? sc[t - off] : 0;
        __syncthreads();
        sc[t] += u;
        __syncthreads();
    }
    if (t < NBKT) bstart[t] = sc[t] - v;
    if (t == 0) offs[N_NODES] = N_EDGES;
}

// ---------------------------------------------------------------------------
// k_place: one block per bucket. Loads bucket entries to LDS, local counting
// sort by node -> per-node offs (global) + final ssrc (ushort) placement.
// ---------------------------------------------------------------------------
__global__ __launch_bounds__(256) void k_place(const unsigned int* __restrict__ bucketed,
                                               const int* __restrict__ gcnt,
                                               const int* __restrict__ bstart,
                                               int* __restrict__ offs,
                                               unsigned short* __restrict__ ssrc) {
    __shared__ unsigned int ent[BKT_CAP];
    __shared__ unsigned short rks[BKT_CAP];
    __shared__ int lcnt[256];
    __shared__ int sc[256];
    __shared__ int lofs[256];

    const int b = blockIdx.x;
    const int t = threadIdx.x;
    const int cnt = min(gcnt[b], BKT_CAP);
    const int gstart = bstart[b];
    const unsigned int* eg = bucketed + (size_t)b * BKT_CAP;

    lcnt[t] = 0;
    __syncthreads();
    for (int i = t; i < cnt; i += 256) {
        unsigned int v = eg[i];
        ent[i] = v;
        int dl = (v >> 16) & 0xFF;
        rks[i] = (unsigned short)atomicAdd(&lcnt[dl], 1);
    }
    __syncthreads();
    sc[t] = lcnt[t];
    __syncthreads();
    for (int off = 1; off < 256; off <<= 1) {
        int u = (t >= off) ? sc[t - off] : 0;
        __syncthreads();
        sc[t] += u;
        __syncthreads();
    }
    lofs[t] = sc[t] - lcnt[t];
    if (t < BKT_NODES) offs[b * BKT_NODES + t] = gstart + lofs[t];
    __syncthreads();
    for (int i = t; i < cnt; i += 256) {
        unsigned int v = ent[i];
        int dl = (v >> 16) & 0xFF;
        int pos = lofs[dl] + (int)rks[i];
        ssrc[gstart + pos] = (unsigned short)(v & 0xFFFF);
    }
}

// ---------------------------------------------------------------------------
// Gather-mean in bf16 (fp32 accumulate). 8 feats/thread (uint4), 4-edge unroll.
// ---------------------------------------------------------------------------
template <int F>
__global__ __launch_bounds__(256) void k_gather_bf(const unsigned short* __restrict__ in,
                                                   int istride,
                                                   unsigned short* __restrict__ out,
                                                   int ostride,
                                                   const int* __restrict__ offs,
                                                   const unsigned short* __restrict__ ssrc) {
    constexpr int TPN = F / 8;
    constexpr int NPB = 256 / TPN;
    int n = blockIdx.x * NPB + threadIdx.x / TPN;
    int f8 = (threadIdx.x % TPN) * 8;
    if (n >= N_NODES) return;
    int s0 = offs[n], s1 = offs[n + 1];
    float a0 = 0.f, a1 = 0.f, a2 = 0.f, a3 = 0.f;
    float a4 = 0.f, a5 = 0.f, a6 = 0.f, a7 = 0.f;
    const unsigned short* inf = in + f8;
    int i = s0;
    for (; i + 4 <= s1; i += 4) {
        int e0 = ssrc[i], e1 = ssrc[i + 1], e2 = ssrc[i + 2], e3 = ssrc[i + 3];
        uint4 v0 = *(const uint4*)&inf[(size_t)e0 * istride];
        uint4 v1 = *(const uint4*)&inf[(size_t)e1 * istride];
        uint4 v2 = *(const uint4*)&inf[(size_t)e2 * istride];
        uint4 v3 = *(const uint4*)&inf[(size_t)e3 * istride];
        a0 += (bf_lo(v0.x) + bf_lo(v1.x)) + (bf_lo(v2.x) + bf_lo(v3.x));
        a1 += (bf_hi(v0.x) + bf_hi(v1.x)) + (bf_hi(v2.x) + bf_hi(v3.x));
        a2 += (bf_lo(v0.y) + bf_lo(v1.y)) + (bf_lo(v2.y) + bf_lo(v3.y));
        a3 += (bf_hi(v0.y) + bf_hi(v1.y)) + (bf_hi(v2.y) + bf_hi(v3.y));
        a4 += (bf_lo(v0.z) + bf_lo(v1.z)) + (bf_lo(v2.z) + bf_lo(v3.z));
        a5 += (bf_hi(v0.z) + bf_hi(v1.z)) + (bf_hi(v2.z) + bf_hi(v3.z));
        a6 += (bf_lo(v0.w) + bf_lo(v1.w)) + (bf_lo(v2.w) + bf_lo(v3.w));
        a7 += (bf_hi(v0.w) + bf_hi(v1.w)) + (bf_hi(v2.w) + bf_hi(v3.w));
    }
    for (; i < s1; ++i) {
        uint4 v = *(const uint4*)&inf[(size_t)ssrc[i] * istride];
        a0 += bf_lo(v.x); a1 += bf_hi(v.x);
        a2 += bf_lo(v.y); a3 += bf_hi(v.y);
        a4 += bf_lo(v.z); a5 += bf_hi(v.z);
        a6 += bf_lo(v.w); a7 += bf_hi(v.w);
    }
    int deg = s1 - s0;
    float scl = (deg > 0) ? 1.f / (float)deg : 0.f;
    uint4 o;
    o.x = pack2bf(a0 * scl, a1 * scl);
    o.y = pack2bf(a2 * scl, a3 * scl);
    o.z = pack2bf(a4 * scl, a5 * scl);
    o.w = pack2bf(a6 * scl, a7 * scl);
    *(uint4*)&out[(size_t)n * ostride + f8] = o;
}

// ---------------------------------------------------------------------------
// bf16 MFMA GEMM (128x128 tile, 4 waves, BK=64, double-buffered 2-phase,
// XOR-swizzle both-sides). C[m][coff+n] = op(A[m,:].W[n,:] + bias[n]).
// ---------------------------------------------------------------------------
template <int KSTEPS, bool RELU, bool BIAS>
__global__ __launch_bounds__(256) void k_gemm_mfma(const unsigned short* __restrict__ A,
                                                   const unsigned short* __restrict__ W,
                                                   const float* __restrict__ bias,
                                                   unsigned short* __restrict__ C,
                                                   int ldc, int coff, int M) {
    constexpr int K = KSTEPS * 64;
    __shared__ unsigned short As[2][128 * 64];
    __shared__ unsigned short Ws[2][128 * 64];

    const int tid = threadIdx.x;
    const int lane = tid & 63;
    const int w = tid >> 6;
    const int row0 = blockIdx.x * 128;
    const int colb = blockIdx.y * 128;

    const int srow_b = w * 32 + (lane >> 3);
    const int slot = lane & 7;

    f32x4 acc[4][4];
#pragma unroll
    for (int i = 0; i < 4; ++i)
#pragma unroll
        for (int j = 0; j < 4; ++j) acc[i][j] = (f32x4){0.f, 0.f, 0.f, 0.f};

    const int m0 = (w >> 1) * 64;
    const int n0 = (w & 1) * 64;

    auto STAGE = [&](int b, int ks) {
        const int kk0 = ks * 64;
#pragma unroll
        for (int it = 0; it < 4; ++it) {
            int r = srow_b + it * 8;
            int sl = (slot ^ (r & 7)) << 3;
            int ra = min(row0 + r, M - 1);
            load_lds16(A + (size_t)ra * K + kk0 + sl,
                       (char*)As[b] + w * 4096 + it * 1024);
            load_lds16(W + (size_t)(colb + r) * K + kk0 + sl,
                       (char*)Ws[b] + w * 4096 + it * 1024);
        }
    };

    STAGE(0, 0);
    __syncthreads();
    int cur = 0;

    for (int ks = 0; ks < KSTEPS; ++ks) {
        if (ks + 1 < KSTEPS) STAGE(cur ^ 1, ks + 1);

        bf16x8 af[4][2], bfr[4][2];
#pragma unroll
        for (int mf = 0; mf < 4; ++mf)
#pragma unroll
            for (int kk = 0; kk < 2; ++kk) {
                int r = m0 + mf * 16 + (lane & 15);
                int sl = (kk * 4 + (lane >> 4)) ^ (r & 7);
                af[mf][kk] = *(const bf16x8*)((const char*)As[cur] + r * 128 + sl * 16);
            }
#pragma unroll
        for (int nf = 0; nf < 4; ++nf)
#pragma unroll
            for (int kk = 0; kk < 2; ++kk) {
                int r = n0 + nf * 16 + (lane & 15);
                int sl = (kk * 4 + (lane >> 4)) ^ (r & 7);
                bfr[nf][kk] = *(const bf16x8*)((const char*)Ws[cur] + r * 128 + sl * 16);
            }
#pragma unroll
        for (int mf = 0; mf < 4; ++mf)
#pragma unroll
            for (int nf = 0; nf < 4; ++nf)
#pragma unroll
                for (int kk = 0; kk < 2; ++kk)
                    acc[mf][nf] = __builtin_amdgcn_mfma_f32_16x16x32_bf16(
                        af[mf][kk], bfr[nf][kk], acc[mf][nf], 0, 0, 0);
        __syncthreads();
        cur ^= 1;
    }

#pragma unroll
    for (int mf = 0; mf < 4; ++mf) {
#pragma unroll
        for (int nf = 0; nf < 4; ++nf) {
            int c = colb + n0 + nf * 16 + (lane & 15);
            float bv = 0.f;
            if constexpr (BIAS) bv = bias[c];
#pragma unroll
            for (int r = 0; r < 4; ++r) {
                int m = row0 + m0 + mf * 16 + ((lane >> 4) << 2) + r;
                if (m < M) {
                    float v = acc[mf][nf][r] + bv;
                    if constexpr (RELU) v = fmaxf(v, 0.f);
                    C[(size_t)m * ldc + coff + c] = f2bf(v);
                }
            }
        }
    }
}

// ---------------------------------------------------------------------------
// Final: h3 = relu(agg3 + b3 + t3r), pooled per-graph sum (batch sorted).
// ---------------------------------------------------------------------------
__global__ __launch_bounds__(256) void k_final(const unsigned short* __restrict__ agg3,
                                               const unsigned short* __restrict__ t3,
                                               const float* __restrict__ b3,
                                               const int* __restrict__ batch,
                                               float* __restrict__ out) {
    const int f = threadIdx.x & 127;
    const int sub = threadIdx.x >> 7;
    const int n0 = blockIdx.x * 64;
    const int nend = min(n0 + 64, N_NODES);
    float local = 0.f;
    int cur = -1;
    float bfv = b3[f];
    for (int n = n0 + sub; n < nend; n += 2) {
        float v = __uint_as_float(((unsigned int)agg3[(size_t)n * 128 + f]) << 16) + bfv +
                  __uint_as_float(((unsigned int)t3[(size_t)n * 256 + 128 + f]) << 16);
        v = fmaxf(v, 0.f);
        int b = batch[n];
        if (b != cur) {
            if (cur >= 0) atomicAdd(&out[(size_t)cur * 128 + f], local);
            local = 0.f;
            cur = b;
        }
        local += v;
    }
    if (cur >= 0) atomicAdd(&out[(size_t)cur * 128 + f], local);
}

// ---------------------------------------------------------------------------
extern "C" void kernel_launch(void* const* d_in, const int* in_sizes, int n_in,
                              void* d_out, int out_size, void* d_ws, size_t ws_size,
                              hipStream_t stream) {
    const float* x   = (const float*)d_in[0];
    const int* ei    = (const int*)d_in[1];
    const int* batch = (const int*)d_in[2];
    const float* W1l = (const float*)d_in[3];
    const float* b1  = (const float*)d_in[4];
    const float* W1r = (const float*)d_in[5];
    const float* W2l = (const float*)d_in[6];
    const float* b2  = (const float*)d_in[7];
    const float* W2r = (const float*)d_in[8];
    const float* W3l = (const float*)d_in[9];
    const float* b3  = (const float*)d_in[10];
    const float* W3r = (const float*)d_in[11];
    const int* src = ei;
    const int* dst = ei + N_EDGES;
    float* out = (float*)d_out;

    size_t off = 0;
    auto carve = [&](size_t bytes) {
        void* p = (char*)d_ws + off;
        off += (bytes + 255) & ~(size_t)255;
        return p;
    };
    int* gcnt   = (int*)carve(256 * 4);
    int* bstart = (int*)carve(256 * 4);
    int* offs   = (int*)carve((size_t)(N_NODES + 1) * 4);
    unsigned short* ssrc = (unsigned short*)carve((size_t)N_EDGES * 2);
    unsigned short* A1   = (unsigned short*)carve((size_t)N_NODES * 256 * 2);  // [agg1|x]
    unsigned short* A2   = (unsigned short*)carve((size_t)N_NODES * 512 * 2);  // [agg2|h1]
    unsigned short* A3   = (unsigned short*)carve((size_t)N_NODES * 256 * 2);  // h2
    // t3 region doubles as the bucketed edge staging (dead before gemm3 writes t3)
    void* t3region = carve((size_t)N_NODES * 256 * 2);  // 25.6MB >= 250*7168*4=7.2MB
    unsigned int* bucketed = (unsigned int*)t3region;
    unsigned short* t3 = (unsigned short*)t3region;
    unsigned short* agg3 = (unsigned short*)carve((size_t)N_NODES * 128 * 2);
    unsigned short* Wp1  = (unsigned short*)carve((size_t)256 * 256 * 2);
    unsigned short* Wp2  = (unsigned short*)carve((size_t)256 * 512 * 2);
    unsigned short* Wp3  = (unsigned short*)carve((size_t)256 * 256 * 2);

    hipMemsetAsync(gcnt, 0, 256 * 4, stream);
    hipMemsetAsync(d_out, 0, (size_t)out_size * 4, stream);

    // CSR build + converts
    k_front<<<NBB + NCVX + NCVW, 256, 0, stream>>>(src, dst, bucketed, gcnt,
                                                   x, A1 + 128,
                                                   W1l, W1r, W2l, W2r, W3l, W3r,
                                                   Wp1, Wp2, Wp3);
    k_bscan<<<1, 256, 0, stream>>>(gcnt, bstart, offs);
    k_place<<<NBKT, 256, 0, stream>>>(bucketed, gcnt, bstart, offs, ssrc);

    const dim3 ggrid((N_NODES + 127) / 128, 2);

    // L1: agg1 = mean(x_bf[src]); h1 = relu([agg1|x] @ Wp1^T + b1) -> A2 cols 256..511
    k_gather_bf<128><<<(N_NODES + 15) / 16, 256, 0, stream>>>(A1 + 128, 256, A1, 256, offs, ssrc);
    k_gemm_mfma<4, true, true><<<ggrid, 256, 0, stream>>>(A1, Wp1, b1, A2, 512, 256, N_NODES);

    // L2: agg2 = mean(h1[src]); h2 = relu([agg2|h1] @ Wp2^T + b2) -> A3
    k_gather_bf<256><<<(N_NODES + 7) / 8, 256, 0, stream>>>(A2 + 256, 512, A2, 512, offs, ssrc);
    k_gemm_mfma<8, true, true><<<ggrid, 256, 0, stream>>>(A2, Wp2, b2, A3, 256, 0, N_NODES);

    // L3: t3 = h2 @ [W3l;W3r]^T ; agg3 = mean(t3l[src]); h3 = relu(agg3+b3+t3r); pool
    k_gemm_mfma<4, false, false><<<ggrid, 256, 0, stream>>>(A3, Wp3, nullptr, t3, 256, 0, N_NODES);
    k_gather_bf<128><<<(N_NODES + 15) / 16, 256, 0, stream>>>(t3, 256, agg3, 128, offs, ssrc);
    k_final<<<(N_NODES + 63) / 64, 256, 0, stream>>>(agg3, t3, b3, batch, out);
}

// Round 7
// 336.337 us; speedup vs baseline: 5.0588x; 1.2764x over previous
//
#include <hip/hip_runtime.h>
#include <hip/hip_bf16.h>

#define N_NODES 50000
#define N_EDGES 1600000
#define N_GRAPHS 64

// bucket sort geometry
#define NBKT 250          // buckets of 200 nodes each (250*200 = 50000)
#define BKT_NODES 200
#define BKT_CAP 7168      // ~+9.6 sigma above mean 6400; guard-checked
#define CHUNK 2048        // edges per k_front bucket block
#define NBB 782           // ceil(1600000/2048)
#define NCVX 6250         // x-convert blocks (50000*128/4 units / 256)
#define NCVW 256          // weight-convert blocks

typedef short bf16x8 __attribute__((ext_vector_type(8)));
typedef float f32x4 __attribute__((ext_vector_type(4)));
typedef float f32x2 __attribute__((ext_vector_type(2)));

__device__ __forceinline__ float bf_lo(unsigned int u) { return __uint_as_float(u << 16); }
__device__ __forceinline__ float bf_hi(unsigned int u) { return __uint_as_float(u & 0xffff0000u); }
__device__ __forceinline__ unsigned short f2bf(float f) {
    unsigned int u = __float_as_uint(f);
    u = (u + 0x7fffu + ((u >> 16) & 1u)) >> 16;
    return (unsigned short)u;
}
__device__ __forceinline__ unsigned int pack2bf(float a, float b) {
    return (unsigned int)f2bf(a) | ((unsigned int)f2bf(b) << 16);
}
// 4 floats -> 4 fp8 e4m3 bytes (one dword)
__device__ __forceinline__ unsigned int pack4fp8(float a, float b, float c, float d) {
    unsigned int q = __builtin_amdgcn_cvt_pk_fp8_f32(a, b, 0, false);
    q = __builtin_amdgcn_cvt_pk_fp8_f32(c, d, q, true);
    return q;
}
__device__ __forceinline__ void load_lds16(const void* g, void* l) {
    __builtin_amdgcn_global_load_lds(
        (const __attribute__((address_space(1))) void*)g,
        (__attribute__((address_space(3))) void*)l, 16, 0, 0);
}

// ---------------------------------------------------------------------------
// k_front: fused {edge bucketing | x->bf16+fp8 convert | weight converts}
// ---------------------------------------------------------------------------
__global__ __launch_bounds__(256) void k_front(
    const int* __restrict__ src, const int* __restrict__ dst,
    unsigned int* __restrict__ bucketed, int* __restrict__ gcnt,
    const float* __restrict__ x, unsigned short* __restrict__ A1x,
    unsigned char* __restrict__ x8,
    const float* __restrict__ W1l, const float* __restrict__ W1r,
    const float* __restrict__ W2l, const float* __restrict__ W2r,
    const float* __restrict__ W3l, const float* __restrict__ W3r,
    unsigned short* __restrict__ Wp1, unsigned short* __restrict__ Wp2,
    unsigned short* __restrict__ Wp3) {
    const int blk = blockIdx.x;
    const int t = threadIdx.x;

    if (blk < NBB) {
        // ---- bucket section: LDS counting sort of a 2048-edge chunk ----
        __shared__ int lcnt[256];
        __shared__ int sc[256];
        __shared__ int lscan[256];
        __shared__ int gb[256];
        __shared__ unsigned int grouped[CHUNK];

        const int base = blk * CHUNK;
        const int ccnt = min(CHUNK, N_EDGES - base);
        lcnt[t] = 0;
        __syncthreads();

        unsigned int pk[CHUNK / 256];
        int rk[CHUNK / 256];
#pragma unroll
        for (int r = 0; r < CHUNK / 256; ++r) {
            int j = r * 256 + t;
            rk[r] = -1;
            if (j < ccnt) {
                int i = base + j;
                int s = src[i];
                int d = dst[i];
                int b = d / BKT_NODES;
                int dl = d - b * BKT_NODES;
                pk[r] = (unsigned int)s | ((unsigned int)dl << 16) | ((unsigned int)b << 24);
                rk[r] = atomicAdd(&lcnt[b], 1);
            }
        }
        __syncthreads();
        sc[t] = lcnt[t];
        __syncthreads();
        for (int off = 1; off < 256; off <<= 1) {
            int v = (t >= off) ? sc[t - off] : 0;
            __syncthreads();
            sc[t] += v;
            __syncthreads();
        }
        lscan[t] = sc[t] - lcnt[t];
        if (t < NBKT && lcnt[t] > 0) gb[t] = atomicAdd(&gcnt[t], lcnt[t]);
        __syncthreads();
#pragma unroll
        for (int r = 0; r < CHUNK / 256; ++r) {
            if (rk[r] >= 0) {
                int b = pk[r] >> 24;
                grouped[lscan[b] + rk[r]] = pk[r];
            }
        }
        __syncthreads();
#pragma unroll
        for (int r = 0; r < CHUNK / 256; ++r) {
            int j = r * 256 + t;
            if (j < ccnt) {
                unsigned int v = grouped[j];
                int b = v >> 24;
                int pos = gb[b] + (j - lscan[b]);
                if (pos < BKT_CAP) bucketed[b * BKT_CAP + pos] = v;
            }
        }
    } else if (blk < NBB + NCVX) {
        // ---- x -> bf16 (A1 right half, stride 256) + fp8 ([50000][128]) ----
        int i = (blk - NBB) * 256 + t;  // unit = 4 floats; exactly 1.6M units
        int r = i >> 5;
        int f4 = (i & 31) << 2;
        float4 v = *(const float4*)&x[(size_t)r * 128 + f4];
        uint2 o;
        o.x = pack2bf(v.x, v.y);
        o.y = pack2bf(v.z, v.w);
        *(uint2*)&A1x[(size_t)r * 256 + f4] = o;
        *(unsigned int*)&x8[(size_t)r * 128 + f4] = pack4fp8(v.x, v.y, v.z, v.w);
    } else {
        // ---- all 6 weight matrices -> packed bf16 ----
        int i = (blk - NBB - NCVX) * 256 + t;  // 0..65535
        const float* srcp;
        unsigned short* dstp;
        int sf4, dstride;
        if (i < 16384) {
            int h = i >> 13;
            i &= 8191;
            srcp = h ? W1r : W1l;
            dstp = Wp1 + (h ? 128 : 0);
            sf4 = 32; dstride = 256;
        } else if (i < 49152) {
            int j = i - 16384;
            int h = j >> 14;
            i = j & 16383;
            srcp = h ? W2r : W2l;
            dstp = Wp2 + (h ? 256 : 0);
            sf4 = 64; dstride = 512;
        } else {
            int j = i - 49152;
            int h = j >> 13;
            i = j & 8191;
            srcp = h ? W3r : W3l;
            dstp = Wp3 + (h ? 128 * 256 : 0);
            sf4 = 64; dstride = 256;
        }
        int r = i / sf4;
        int f4 = (i % sf4) * 4;
        float4 v = *(const float4*)&srcp[(size_t)r * (sf4 * 4) + f4];
        uint2 o;
        o.x = pack2bf(v.x, v.y);
        o.y = pack2bf(v.z, v.w);
        *(uint2*)&dstp[(size_t)r * dstride + f4] = o;
    }
}

// ---------------------------------------------------------------------------
// k_place: one block per bucket. Scans the 250 bucket counts locally (no
// separate bscan), then LDS counting sort by node -> offs + ssrc (ushort).
// ---------------------------------------------------------------------------
__global__ __launch_bounds__(256) void k_place(const unsigned int* __restrict__ bucketed,
                                               const int* __restrict__ gcnt,
                                               int* __restrict__ offs,
                                               unsigned short* __restrict__ ssrc) {
    __shared__ unsigned int ent[BKT_CAP];
    __shared__ unsigned short rks[BKT_CAP];
    __shared__ int lcnt[256];
    __shared__ int sc[256];
    __shared__ int lofs[256];
    __shared__ int excl[256];

    const int b = blockIdx.x;
    const int t = threadIdx.x;

    // local scan of all bucket counts -> this bucket's global start
    int gv = (t < NBKT) ? gcnt[t] : 0;
    sc[t] = gv;
    __syncthreads();
    for (int off = 1; off < 256; off <<= 1) {
        int u = (t >= off) ? sc[t - off] : 0;
        __syncthreads();
        sc[t] += u;
        __syncthreads();
    }
    excl[t] = sc[t] - gv;
    __syncthreads();
    const int gstart = excl[b];
    const int cnt = min(gcnt[b], BKT_CAP);
    if (b == 0 && t == 0) offs[N_NODES] = N_EDGES;

    const unsigned int* eg = bucketed + (size_t)b * BKT_CAP;
    lcnt[t] = 0;
    __syncthreads();
    for (int i = t; i < cnt; i += 256) {
        unsigned int v = eg[i];
        ent[i] = v;
        int dl = (v >> 16) & 0xFF;
        rks[i] = (unsigned short)atomicAdd(&lcnt[dl], 1);
    }
    __syncthreads();
    sc[t] = lcnt[t];
    __syncthreads();
    for (int off = 1; off < 256; off <<= 1) {
        int u = (t >= off) ? sc[t - off] : 0;
        __syncthreads();
        sc[t] += u;
        __syncthreads();
    }
    lofs[t] = sc[t] - lcnt[t];
    if (t < BKT_NODES) offs[b * BKT_NODES + t] = gstart + lofs[t];
    __syncthreads();
    for (int i = t; i < cnt; i += 256) {
        unsigned int v = ent[i];
        int dl = (v >> 16) & 0xFF;
        int pos = lofs[dl] + (int)rks[i];
        ssrc[gstart + pos] = (unsigned short)(v & 0xFFFF);
    }
}

// ---------------------------------------------------------------------------
// bf16 -> fp8 convert pass (8 elems/thread). in: bf16 row stride istride,
// reading `width` cols; out: compact fp8 [N][width].
// ---------------------------------------------------------------------------
__global__ __launch_bounds__(256) void k_cvt8(const unsigned short* __restrict__ in,
                                              int istride, int width,
                                              unsigned char* __restrict__ out,
                                              int total8) {
    int i = blockIdx.x * 256 + threadIdx.x;
    if (i >= total8) return;
    int w8 = width >> 3;
    int r = i / w8;
    int c8 = (i - r * w8) << 3;
    uint4 v = *(const uint4*)&in[(size_t)r * istride + c8];
    uint2 q;
    q.x = pack4fp8(bf_lo(v.x), bf_hi(v.x), bf_lo(v.y), bf_hi(v.y));
    q.y = pack4fp8(bf_lo(v.z), bf_hi(v.z), bf_lo(v.w), bf_hi(v.w));
    *(uint2*)&out[(size_t)r * width + c8] = q;
}

// ---------------------------------------------------------------------------
// fp8 gather-mean -> bf16 out. Input rows compact [*, F] fp8. 16 fp8/thread
// (uint4 loads), 4-edge unroll.
// ---------------------------------------------------------------------------
#define DEC_ADD(dw, base)                                             \
    {                                                                 \
        f32x2 lo_ = __builtin_amdgcn_cvt_pk_f32_fp8((dw), false);     \
        f32x2 hi_ = __builtin_amdgcn_cvt_pk_f32_fp8((dw), true);      \
        a[(base) + 0] += lo_.x;                                       \
        a[(base) + 1] += lo_.y;                                       \
        a[(base) + 2] += hi_.x;                                       \
        a[(base) + 3] += hi_.y;                                       \
    }

template <int F>
__global__ __launch_bounds__(256) void k_gather8(const unsigned char* __restrict__ in,
                                                 unsigned short* __restrict__ out,
                                                 int ostride,
                                                 const int* __restrict__ offs,
                                                 const unsigned short* __restrict__ ssrc) {
    constexpr int TPN = F / 16;
    constexpr int NPB = 256 / TPN;
    int n = blockIdx.x * NPB + threadIdx.x / TPN;
    int f16 = (threadIdx.x % TPN) * 16;
    if (n >= N_NODES) return;
    int s0 = offs[n], s1 = offs[n + 1];
    float a[16];
#pragma unroll
    for (int j = 0; j < 16; ++j) a[j] = 0.f;
    const unsigned char* inf = in + f16;
    int i = s0;
    for (; i + 4 <= s1; i += 4) {
        int e0 = ssrc[i], e1 = ssrc[i + 1], e2 = ssrc[i + 2], e3 = ssrc[i + 3];
        uint4 v0 = *(const uint4*)&inf[(size_t)e0 * F];
        uint4 v1 = *(const uint4*)&inf[(size_t)e1 * F];
        uint4 v2 = *(const uint4*)&inf[(size_t)e2 * F];
        uint4 v3 = *(const uint4*)&inf[(size_t)e3 * F];
        DEC_ADD(v0.x, 0) DEC_ADD(v0.y, 4) DEC_ADD(v0.z, 8) DEC_ADD(v0.w, 12)
        DEC_ADD(v1.x, 0) DEC_ADD(v1.y, 4) DEC_ADD(v1.z, 8) DEC_ADD(v1.w, 12)
        DEC_ADD(v2.x, 0) DEC_ADD(v2.y, 4) DEC_ADD(v2.z, 8) DEC_ADD(v2.w, 12)
        DEC_ADD(v3.x, 0) DEC_ADD(v3.y, 4) DEC_ADD(v3.z, 8) DEC_ADD(v3.w, 12)
    }
    for (; i < s1; ++i) {
        uint4 v = *(const uint4*)&inf[(size_t)ssrc[i] * F];
        DEC_ADD(v.x, 0) DEC_ADD(v.y, 4) DEC_ADD(v.z, 8) DEC_ADD(v.w, 12)
    }
    int deg = s1 - s0;
    float scl = (deg > 0) ? 1.f / (float)deg : 0.f;
    uint4 o0, o1;
    o0.x = pack2bf(a[0] * scl, a[1] * scl);
    o0.y = pack2bf(a[2] * scl, a[3] * scl);
    o0.z = pack2bf(a[4] * scl, a[5] * scl);
    o0.w = pack2bf(a[6] * scl, a[7] * scl);
    o1.x = pack2bf(a[8] * scl, a[9] * scl);
    o1.y = pack2bf(a[10] * scl, a[11] * scl);
    o1.z = pack2bf(a[12] * scl, a[13] * scl);
    o1.w = pack2bf(a[14] * scl, a[15] * scl);
    *(uint4*)&out[(size_t)n * ostride + f16] = o0;
    *(uint4*)&out[(size_t)n * ostride + f16 + 8] = o1;
}

// ---------------------------------------------------------------------------
// bf16 MFMA GEMM (128x128 tile, 4 waves, BK=64, double-buffered 2-phase,
// XOR-swizzle both-sides). C[m][coff+n] = op(A[m,:].W[n,:] + bias[n]).
// ---------------------------------------------------------------------------
template <int KSTEPS, bool RELU, bool BIAS>
__global__ __launch_bounds__(256) void k_gemm_mfma(const unsigned short* __restrict__ A,
                                                   const unsigned short* __restrict__ W,
                                                   const float* __restrict__ bias,
                                                   unsigned short* __restrict__ C,
                                                   int ldc, int coff, int M) {
    constexpr int K = KSTEPS * 64;
    __shared__ unsigned short As[2][128 * 64];
    __shared__ unsigned short Ws[2][128 * 64];

    const int tid = threadIdx.x;
    const int lane = tid & 63;
    const int w = tid >> 6;
    const int row0 = blockIdx.x * 128;
    const int colb = blockIdx.y * 128;

    const int srow_b = w * 32 + (lane >> 3);
    const int slot = lane & 7;

    f32x4 acc[4][4];
#pragma unroll
    for (int i = 0; i < 4; ++i)
#pragma unroll
        for (int j = 0; j < 4; ++j) acc[i][j] = (f32x4){0.f, 0.f, 0.f, 0.f};

    const int m0 = (w >> 1) * 64;
    const int n0 = (w & 1) * 64;

    auto STAGE = [&](int b, int ks) {
        const int kk0 = ks * 64;
#pragma unroll
        for (int it = 0; it < 4; ++it) {
            int r = srow_b + it * 8;
            int sl = (slot ^ (r & 7)) << 3;
            int ra = min(row0 + r, M - 1);
            load_lds16(A + (size_t)ra * K + kk0 + sl,
                       (char*)As[b] + w * 4096 + it * 1024);
            load_lds16(W + (size_t)(colb + r) * K + kk0 + sl,
                       (char*)Ws[b] + w * 4096 + it * 1024);
        }
    };

    STAGE(0, 0);
    __syncthreads();
    int cur = 0;

    for (int ks = 0; ks < KSTEPS; ++ks) {
        if (ks + 1 < KSTEPS) STAGE(cur ^ 1, ks + 1);

        bf16x8 af[4][2], bfr[4][2];
#pragma unroll
        for (int mf = 0; mf < 4; ++mf)
#pragma unroll
            for (int kk = 0; kk < 2; ++kk) {
                int r = m0 + mf * 16 + (lane & 15);
                int sl = (kk * 4 + (lane >> 4)) ^ (r & 7);
                af[mf][kk] = *(const bf16x8*)((const char*)As[cur] + r * 128 + sl * 16);
            }
#pragma unroll
        for (int nf = 0; nf < 4; ++nf)
#pragma unroll
            for (int kk = 0; kk < 2; ++kk) {
                int r = n0 + nf * 16 + (lane & 15);
                int sl = (kk * 4 + (lane >> 4)) ^ (r & 7);
                bfr[nf][kk] = *(const bf16x8*)((const char*)Ws[cur] + r * 128 + sl * 16);
            }
#pragma unroll
        for (int mf = 0; mf < 4; ++mf)
#pragma unroll
            for (int nf = 0; nf < 4; ++nf)
#pragma unroll
                for (int kk = 0; kk < 2; ++kk)
                    acc[mf][nf] = __builtin_amdgcn_mfma_f32_16x16x32_bf16(
                        af[mf][kk], bfr[nf][kk], acc[mf][nf], 0, 0, 0);
        __syncthreads();
        cur ^= 1;
    }

#pragma unroll
    for (int mf = 0; mf < 4; ++mf) {
#pragma unroll
        for (int nf = 0; nf < 4; ++nf) {
            int c = colb + n0 + nf * 16 + (lane & 15);
            float bv = 0.f;
            if constexpr (BIAS) bv = bias[c];
#pragma unroll
            for (int r = 0; r < 4; ++r) {
                int m = row0 + m0 + mf * 16 + ((lane >> 4) << 2) + r;
                if (m < M) {
                    float v = acc[mf][nf][r] + bv;
                    if constexpr (RELU) v = fmaxf(v, 0.f);
                    C[(size_t)m * ldc + coff + c] = f2bf(v);
                }
            }
        }
    }
}

// ---------------------------------------------------------------------------
// Fused final: gather3 (fp8 t3l) + h3 = relu(agg3 + b3 + t3r) + per-graph pool.
// 16 nodes/block, 16 threads/node (8 feats each); LDS stage then run-length
// atomics by 128 threads. 3125 blocks * 16 = 50000 exactly.
// ---------------------------------------------------------------------------
__global__ __launch_bounds__(256) void k_final8(const unsigned char* __restrict__ t3l8,
                                                const unsigned short* __restrict__ t3,
                                                const float* __restrict__ b3,
                                                const int* __restrict__ offs,
                                                const unsigned short* __restrict__ ssrc,
                                                const int* __restrict__ batch,
                                                float* __restrict__ out) {
    __shared__ float sm[16][128];
    __shared__ int bsh[16];
    const int t = threadIdx.x;
    const int sub = t >> 4;
    const int f8 = (t & 15) * 8;
    const int n = blockIdx.x * 16 + sub;

    int s0 = offs[n], s1 = offs[n + 1];
    float a[8];
#pragma unroll
    for (int j = 0; j < 8; ++j) a[j] = 0.f;
    const unsigned char* inf = t3l8 + f8;
    int i = s0;
    for (; i + 4 <= s1; i += 4) {
        int e0 = ssrc[i], e1 = ssrc[i + 1], e2 = ssrc[i + 2], e3 = ssrc[i + 3];
        uint2 v0 = *(const uint2*)&inf[(size_t)e0 * 128];
        uint2 v1 = *(const uint2*)&inf[(size_t)e1 * 128];
        uint2 v2 = *(const uint2*)&inf[(size_t)e2 * 128];
        uint2 v3 = *(const uint2*)&inf[(size_t)e3 * 128];
        DEC_ADD(v0.x, 0) DEC_ADD(v0.y, 4)
        DEC_ADD(v1.x, 0) DEC_ADD(v1.y, 4)
        DEC_ADD(v2.x, 0) DEC_ADD(v2.y, 4)
        DEC_ADD(v3.x, 0) DEC_ADD(v3.y, 4)
    }
    for (; i < s1; ++i) {
        uint2 v = *(const uint2*)&inf[(size_t)ssrc[i] * 128];
        DEC_ADD(v.x, 0) DEC_ADD(v.y, 4)
    }
    int deg = s1 - s0;
    float scl = (deg > 0) ? 1.f / (float)deg : 0.f;
    float4 bv0 = *(const float4*)&b3[f8];
    float4 bv1 = *(const float4*)&b3[f8 + 4];
    uint4 tr = *(const uint4*)&t3[(size_t)n * 256 + 128 + f8];
    float tv[8] = {bf_lo(tr.x), bf_hi(tr.x), bf_lo(tr.y), bf_hi(tr.y),
                   bf_lo(tr.z), bf_hi(tr.z), bf_lo(tr.w), bf_hi(tr.w)};
    float bb[8] = {bv0.x, bv0.y, bv0.z, bv0.w, bv1.x, bv1.y, bv1.z, bv1.w};
#pragma unroll
    for (int j = 0; j < 8; ++j)
        sm[sub][f8 + j] = fmaxf(a[j] * scl + bb[j] + tv[j], 0.f);
    if ((t & 15) == 0) bsh[sub] = batch[n];
    __syncthreads();

    if (t < 128) {
        float local = 0.f;
        int cur = -1;
#pragma unroll
        for (int k = 0; k < 16; ++k) {
            int b = bsh[k];
            if (b != cur) {
                if (cur >= 0) atomicAdd(&out[(size_t)cur * 128 + t], local);
                local = 0.f;
                cur = b;
            }
            local += sm[k][t];
        }
        if (cur >= 0) atomicAdd(&out[(size_t)cur * 128 + t], local);
    }
}

// ---------------------------------------------------------------------------
extern "C" void kernel_launch(void* const* d_in, const int* in_sizes, int n_in,
                              void* d_out, int out_size, void* d_ws, size_t ws_size,
                              hipStream_t stream) {
    const float* x   = (const float*)d_in[0];
    const int* ei    = (const int*)d_in[1];
    const int* batch = (const int*)d_in[2];
    const float* W1l = (const float*)d_in[3];
    const float* b1  = (const float*)d_in[4];
    const float* W1r = (const float*)d_in[5];
    const float* W2l = (const float*)d_in[6];
    const float* b2  = (const float*)d_in[7];
    const float* W2r = (const float*)d_in[8];
    const float* W3l = (const float*)d_in[9];
    const float* b3  = (const float*)d_in[10];
    const float* W3r = (const float*)d_in[11];
    const int* src = ei;
    const int* dst = ei + N_EDGES;
    float* out = (float*)d_out;

    size_t off = 0;
    auto carve = [&](size_t bytes) {
        void* p = (char*)d_ws + off;
        off += (bytes + 255) & ~(size_t)255;
        return p;
    };
    int* gcnt   = (int*)carve(256 * 4);
    int* offs   = (int*)carve((size_t)(N_NODES + 1) * 4);
    unsigned short* ssrc = (unsigned short*)carve((size_t)N_EDGES * 2);
    unsigned short* A1   = (unsigned short*)carve((size_t)N_NODES * 256 * 2);  // [agg1|x]
    unsigned short* A2   = (unsigned short*)carve((size_t)N_NODES * 512 * 2);  // [agg2|h1]
    unsigned short* A3   = (unsigned short*)carve((size_t)N_NODES * 256 * 2);  // h2
    // t3 region doubles as the bucketed edge staging (dead before gemm3 writes t3)
    void* t3region = carve((size_t)N_NODES * 256 * 2);  // 25.6MB >= 250*7168*4=7.2MB
    unsigned int* bucketed = (unsigned int*)t3region;
    unsigned short* t3 = (unsigned short*)t3region;
    unsigned char* x8   = (unsigned char*)carve((size_t)N_NODES * 128);
    unsigned char* h18  = (unsigned char*)carve((size_t)N_NODES * 256);
    unsigned char* t3l8 = (unsigned char*)carve((size_t)N_NODES * 128);
    unsigned short* Wp1 = (unsigned short*)carve((size_t)256 * 256 * 2);
    unsigned short* Wp2 = (unsigned short*)carve((size_t)256 * 512 * 2);
    unsigned short* Wp3 = (unsigned short*)carve((size_t)256 * 256 * 2);

    hipMemsetAsync(gcnt, 0, 256 * 4, stream);
    hipMemsetAsync(d_out, 0, (size_t)out_size * 4, stream);

    // CSR build + converts (x -> bf16 + fp8, weights -> bf16)
    k_front<<<NBB + NCVX + NCVW, 256, 0, stream>>>(src, dst, bucketed, gcnt,
                                                   x, A1 + 128, x8,
                                                   W1l, W1r, W2l, W2r, W3l, W3r,
                                                   Wp1, Wp2, Wp3);
    k_place<<<NBKT, 256, 0, stream>>>(bucketed, gcnt, offs, ssrc);

    const dim3 ggrid((N_NODES + 127) / 128, 2);

    // L1: agg1 = mean(x8[src]) -> A1 left; h1 = relu([agg1|x]@Wp1^T+b1) -> A2 right
    k_gather8<128><<<(N_NODES + 31) / 32, 256, 0, stream>>>(x8, A1, 256, offs, ssrc);
    k_gemm_mfma<4, true, true><<<ggrid, 256, 0, stream>>>(A1, Wp1, b1, A2, 512, 256, N_NODES);

    // L2: h1 -> fp8; agg2 = mean(h18[src]) -> A2 left; h2 = relu([agg2|h1]@Wp2^T+b2)
    k_cvt8<<<(N_NODES * 32 + 255) / 256, 256, 0, stream>>>(A2 + 256, 512, 256, h18, N_NODES * 32);
    k_gather8<256><<<(N_NODES + 15) / 16, 256, 0, stream>>>(h18, A2, 512, offs, ssrc);
    k_gemm_mfma<8, true, true><<<ggrid, 256, 0, stream>>>(A2, Wp2, b2, A3, 256, 0, N_NODES);

    // L3: t3 = h2 @ [W3l;W3r]^T; t3l -> fp8; fused gather+relu+pool
    k_gemm_mfma<4, false, false><<<ggrid, 256, 0, stream>>>(A3, Wp3, nullptr, t3, 256, 0, N_NODES);
    k_cvt8<<<(N_NODES * 16 + 255) / 256, 256, 0, stream>>>(t3, 256, 128, t3l8, N_NODES * 16);
    k_final8<<<N_NODES / 16, 256, 0, stream>>>(t3l8, t3, b3, offs, ssrc, batch, out);
}

// Round 8
// 319.784 us; speedup vs baseline: 5.3207x; 1.0518x over previous
//
#include <hip/hip_runtime.h>
#include <hip/hip_bf16.h>

#define N_NODES 50000
#define N_EDGES 1600000
#define N_GRAPHS 64

// bucket sort geometry
#define NBKT 250          // buckets of 200 nodes each
#define BKT_NODES 200
#define BKT_CAP 7168      // mean 6400, sigma ~80; +9.6 sigma; guard-checked
#define CHUNK 4096        // edges per k_front bucket block
#define NBB 391           // ceil(1600000/4096)
#define NCVX 6250         // x-convert blocks
#define NCVW 256          // weight-convert blocks
#define ZROW N_NODES      // zero-row index for gather padding

typedef short bf16x8 __attribute__((ext_vector_type(8)));
typedef float f32x4 __attribute__((ext_vector_type(4)));
typedef float f32x2 __attribute__((ext_vector_type(2)));

__device__ __forceinline__ float bf_lo(unsigned int u) { return __uint_as_float(u << 16); }
__device__ __forceinline__ float bf_hi(unsigned int u) { return __uint_as_float(u & 0xffff0000u); }
__device__ __forceinline__ unsigned short f2bf(float f) {
    unsigned int u = __float_as_uint(f);
    u = (u + 0x7fffu + ((u >> 16) & 1u)) >> 16;
    return (unsigned short)u;
}
__device__ __forceinline__ unsigned int pack2bf(float a, float b) {
    return (unsigned int)f2bf(a) | ((unsigned int)f2bf(b) << 16);
}
__device__ __forceinline__ unsigned int pack4fp8(float a, float b, float c, float d) {
    unsigned int q = __builtin_amdgcn_cvt_pk_fp8_f32(a, b, 0, false);
    q = __builtin_amdgcn_cvt_pk_fp8_f32(c, d, q, true);
    return q;
}
__device__ __forceinline__ void load_lds16(const void* g, void* l) {
    __builtin_amdgcn_global_load_lds(
        (const __attribute__((address_space(1))) void*)g,
        (__attribute__((address_space(3))) void*)l, 16, 0, 0);
}

// ---------------------------------------------------------------------------
// k_front: fused {edge bucketing | x->bf16+fp8 convert | weight converts}
// ---------------------------------------------------------------------------
__global__ __launch_bounds__(256) void k_front(
    const int* __restrict__ src, const int* __restrict__ dst,
    unsigned int* __restrict__ bucketed, int* __restrict__ gcnt,
    const float* __restrict__ x, unsigned short* __restrict__ A1x,
    unsigned char* __restrict__ x8,
    const float* __restrict__ W1l, const float* __restrict__ W1r,
    const float* __restrict__ W2l, const float* __restrict__ W2r,
    const float* __restrict__ W3l, const float* __restrict__ W3r,
    unsigned short* __restrict__ Wp1, unsigned short* __restrict__ Wp2,
    unsigned short* __restrict__ Wp3) {
    const int blk = blockIdx.x;
    const int t = threadIdx.x;

    if (blk < NBB) {
        __shared__ int lcnt[256];
        __shared__ int sc[256];
        __shared__ int lscan[256];
        __shared__ int gb[256];
        __shared__ unsigned int grouped[CHUNK];

        const int base = blk * CHUNK;
        const int ccnt = min(CHUNK, N_EDGES - base);
        lcnt[t] = 0;
        __syncthreads();

        unsigned int pk[CHUNK / 256];
        int rk[CHUNK / 256];
#pragma unroll
        for (int r = 0; r < CHUNK / 256; ++r) {
            int j = r * 256 + t;
            rk[r] = -1;
            if (j < ccnt) {
                int i = base + j;
                int s = src[i];
                int d = dst[i];
                int b = d / BKT_NODES;
                int dl = d - b * BKT_NODES;
                pk[r] = (unsigned int)s | ((unsigned int)dl << 16) | ((unsigned int)b << 24);
                rk[r] = atomicAdd(&lcnt[b], 1);
            }
        }
        __syncthreads();
        sc[t] = lcnt[t];
        __syncthreads();
        for (int off = 1; off < 256; off <<= 1) {
            int v = (t >= off) ? sc[t - off] : 0;
            __syncthreads();
            sc[t] += v;
            __syncthreads();
        }
        lscan[t] = sc[t] - lcnt[t];
        if (t < NBKT && lcnt[t] > 0) gb[t] = atomicAdd(&gcnt[t], lcnt[t]);
        __syncthreads();
#pragma unroll
        for (int r = 0; r < CHUNK / 256; ++r) {
            if (rk[r] >= 0) {
                int b = pk[r] >> 24;
                grouped[lscan[b] + rk[r]] = pk[r];
            }
        }
        __syncthreads();
#pragma unroll
        for (int r = 0; r < CHUNK / 256; ++r) {
            int j = r * 256 + t;
            if (j < ccnt) {
                unsigned int v = grouped[j];
                int b = v >> 24;
                int pos = gb[b] + (j - lscan[b]);
                if (pos < BKT_CAP) bucketed[b * BKT_CAP + pos] = v;
            }
        }
    } else if (blk < NBB + NCVX) {
        // ---- x -> bf16 (A1 right half, stride 256) + fp8 ([.][128]) ----
        int i = (blk - NBB) * 256 + t;  // exactly 1.6M units of 4 floats
        int r = i >> 5;
        int f4 = (i & 31) << 2;
        float4 v = *(const float4*)&x[(size_t)r * 128 + f4];
        uint2 o;
        o.x = pack2bf(v.x, v.y);
        o.y = pack2bf(v.z, v.w);
        *(uint2*)&A1x[(size_t)r * 256 + f4] = o;
        *(unsigned int*)&x8[(size_t)r * 128 + f4] = pack4fp8(v.x, v.y, v.z, v.w);
    } else {
        // ---- all 6 weight matrices -> packed bf16 ----
        int i = (blk - NBB - NCVX) * 256 + t;  // 0..65535
        const float* srcp;
        unsigned short* dstp;
        int sf4, dstride;
        if (i < 16384) {
            int h = i >> 13;
            i &= 8191;
            srcp = h ? W1r : W1l;
            dstp = Wp1 + (h ? 128 : 0);
            sf4 = 32; dstride = 256;
        } else if (i < 49152) {
            int j = i - 16384;
            int h = j >> 14;
            i = j & 16383;
            srcp = h ? W2r : W2l;
            dstp = Wp2 + (h ? 256 : 0);
            sf4 = 64; dstride = 512;
        } else {
            int j = i - 49152;
            int h = j >> 13;
            i = j & 8191;
            srcp = h ? W3r : W3l;
            dstp = Wp3 + (h ? 128 * 256 : 0);
            sf4 = 64; dstride = 256;
        }
        int r = i / sf4;
        int f4 = (i % sf4) * 4;
        float4 v = *(const float4*)&srcp[(size_t)r * (sf4 * 4) + f4];
        uint2 o;
        o.x = pack2bf(v.x, v.y);
        o.y = pack2bf(v.z, v.w);
        *(uint2*)&dstp[(size_t)r * dstride + f4] = o;
    }
}

// ---------------------------------------------------------------------------
// k_place: one block (512 thr) per bucket. Slack-scan of bucket counts ->
// global start; LDS counting sort by node -> offs/deg + padded ssrc.
// Segments padded to x4 with ZROW entries; slack layout (gcnt[b]+600).
// ---------------------------------------------------------------------------
__global__ __launch_bounds__(512) void k_place(const unsigned int* __restrict__ bucketed,
                                               const int* __restrict__ gcnt,
                                               int* __restrict__ offs,
                                               unsigned short* __restrict__ deg,
                                               unsigned short* __restrict__ ssrc) {
    __shared__ unsigned int ent[BKT_CAP];
    __shared__ unsigned short rks[BKT_CAP];
    __shared__ int lcnt[256];
    __shared__ int sc[256];
    __shared__ int lofs[256];
    __shared__ int gs;

    const int b = blockIdx.x;
    const int t = threadIdx.x;

    // slack scan (inclusive) over per-bucket upper bounds
    if (t < 256) sc[t] = (t < NBKT) ? (gcnt[t] + 3 * BKT_NODES) : 0;
    __syncthreads();
    for (int off = 1; off < 256; off <<= 1) {
        int u = 0;
        if (t < 256 && t >= off) u = sc[t - off];
        __syncthreads();
        if (t < 256) sc[t] += u;
        __syncthreads();
    }
    if (t == 0) gs = (b == 0) ? 0 : sc[b - 1];
    if (t < 256) lcnt[t] = 0;
    __syncthreads();

    const int cnt = min(gcnt[b], BKT_CAP);
    const unsigned int* eg = bucketed + (size_t)b * BKT_CAP;
    for (int i = t; i < cnt; i += 512) {
        unsigned int v = eg[i];
        ent[i] = v;
        int dl = (v >> 16) & 0xFF;
        rks[i] = (unsigned short)atomicAdd(&lcnt[dl], 1);
    }
    __syncthreads();
    // padded exclusive scan of per-node counts
    int pc = 0;
    if (t < 256) {
        pc = (lcnt[t] + 3) & ~3;
        sc[t] = pc;
    }
    __syncthreads();
    for (int off = 1; off < 256; off <<= 1) {
        int u = 0;
        if (t < 256 && t >= off) u = sc[t - off];
        __syncthreads();
        if (t < 256) sc[t] += u;
        __syncthreads();
    }
    if (t < 256) lofs[t] = sc[t] - pc;
    __syncthreads();
    const int gstart = gs;
    if (t < BKT_NODES) {
        offs[b * BKT_NODES + t] = gstart + lofs[t];
        deg[b * BKT_NODES + t] = (unsigned short)lcnt[t];
    }
    for (int i = t; i < cnt; i += 512) {
        unsigned int v = ent[i];
        int dl = (v >> 16) & 0xFF;
        ssrc[gstart + lofs[dl] + (int)rks[i]] = (unsigned short)(v & 0xFFFF);
    }
    if (t < BKT_NODES) {
        int d = lcnt[t], pd = (d + 3) & ~3;
        int base = gstart + lofs[t];
        for (int j = d; j < pd; ++j) ssrc[base + j] = (unsigned short)ZROW;
    }
}

// ---------------------------------------------------------------------------
// fp8 gather-mean -> bf16. Padded segments (x4, ZROW), 16 fp8/thread.
// ---------------------------------------------------------------------------
#define DEC_ADD(dw, base)                                             \
    {                                                                 \
        f32x2 lo_ = __builtin_amdgcn_cvt_pk_f32_fp8((dw), false);     \
        f32x2 hi_ = __builtin_amdgcn_cvt_pk_f32_fp8((dw), true);      \
        a[(base) + 0] += lo_.x;                                       \
        a[(base) + 1] += lo_.y;                                       \
        a[(base) + 2] += hi_.x;                                       \
        a[(base) + 3] += hi_.y;                                       \
    }

template <int F>
__global__ __launch_bounds__(256) void k_gather8(const unsigned char* __restrict__ in,
                                                 unsigned short* __restrict__ out,
                                                 int ostride,
                                                 const int* __restrict__ offs,
                                                 const unsigned short* __restrict__ deg,
                                                 const unsigned short* __restrict__ ssrc) {
    constexpr int TPN = F / 16;
    constexpr int NPB = 256 / TPN;
    int n = blockIdx.x * NPB + threadIdx.x / TPN;
    int f16 = (threadIdx.x % TPN) * 16;
    if (n >= N_NODES) return;
    int s0 = offs[n];
    int d = deg[n];
    int pd = (d + 3) & ~3;
    float a[16];
#pragma unroll
    for (int j = 0; j < 16; ++j) a[j] = 0.f;
    const unsigned char* inf = in + f16;
    for (int i = s0; i < s0 + pd; i += 4) {
        int e0 = ssrc[i], e1 = ssrc[i + 1], e2 = ssrc[i + 2], e3 = ssrc[i + 3];
        uint4 v0 = *(const uint4*)&inf[(size_t)e0 * F];
        uint4 v1 = *(const uint4*)&inf[(size_t)e1 * F];
        uint4 v2 = *(const uint4*)&inf[(size_t)e2 * F];
        uint4 v3 = *(const uint4*)&inf[(size_t)e3 * F];
        DEC_ADD(v0.x, 0) DEC_ADD(v0.y, 4) DEC_ADD(v0.z, 8) DEC_ADD(v0.w, 12)
        DEC_ADD(v1.x, 0) DEC_ADD(v1.y, 4) DEC_ADD(v1.z, 8) DEC_ADD(v1.w, 12)
        DEC_ADD(v2.x, 0) DEC_ADD(v2.y, 4) DEC_ADD(v2.z, 8) DEC_ADD(v2.w, 12)
        DEC_ADD(v3.x, 0) DEC_ADD(v3.y, 4) DEC_ADD(v3.z, 8) DEC_ADD(v3.w, 12)
    }
    float scl = (d > 0) ? 1.f / (float)d : 0.f;
    uint4 o0, o1;
    o0.x = pack2bf(a[0] * scl, a[1] * scl);
    o0.y = pack2bf(a[2] * scl, a[3] * scl);
    o0.z = pack2bf(a[4] * scl, a[5] * scl);
    o0.w = pack2bf(a[6] * scl, a[7] * scl);
    o1.x = pack2bf(a[8] * scl, a[9] * scl);
    o1.y = pack2bf(a[10] * scl, a[11] * scl);
    o1.z = pack2bf(a[12] * scl, a[13] * scl);
    o1.w = pack2bf(a[14] * scl, a[15] * scl);
    *(uint4*)&out[(size_t)n * ostride + f16] = o0;
    *(uint4*)&out[(size_t)n * ostride + f16 + 8] = o1;
}

// ---------------------------------------------------------------------------
// bf16 MFMA GEMM (128x128 tile, 4 waves, BK=64, dbuf 2-phase, XOR-swizzle).
// C[m][coff+n] = op(A[m,:].W[n,:] + bias[n]).  FP8W>0: also emit fp8 copy of
// op(...) into fp8out[m][colb..colb+127] (row width FP8W) via LDS transpose.
// ---------------------------------------------------------------------------
template <int KSTEPS, bool RELU, bool BIAS, int FP8W>
__global__ __launch_bounds__(256) void k_gemm_mfma(const unsigned short* __restrict__ A,
                                                   const unsigned short* __restrict__ W,
                                                   const float* __restrict__ bias,
                                                   unsigned short* __restrict__ C,
                                                   int ldc, int coff,
                                                   unsigned char* __restrict__ fp8out,
                                                   int M) {
    constexpr int K = KSTEPS * 64;
    __shared__ unsigned short SH[32768];  // As0|As1|Ws0|Ws1 (16KB each)

    const int tid = threadIdx.x;
    const int lane = tid & 63;
    const int w = tid >> 6;
    const int row0 = blockIdx.x * 128;
    const int colb = blockIdx.y * 128;

    const int srow_b = w * 32 + (lane >> 3);
    const int slot = lane & 7;

    f32x4 acc[4][4];
#pragma unroll
    for (int i = 0; i < 4; ++i)
#pragma unroll
        for (int j = 0; j < 4; ++j) acc[i][j] = (f32x4){0.f, 0.f, 0.f, 0.f};

    const int m0 = (w >> 1) * 64;
    const int n0 = (w & 1) * 64;

    auto STAGE = [&](int b, int ks) {
        const int kk0 = ks * 64;
#pragma unroll
        for (int it = 0; it < 4; ++it) {
            int r = srow_b + it * 8;
            int sl = (slot ^ (r & 7)) << 3;
            int ra = min(row0 + r, M - 1);
            load_lds16(A + (size_t)ra * K + kk0 + sl,
                       (char*)SH + b * 16384 + w * 4096 + it * 1024);
            load_lds16(W + (size_t)(colb + r) * K + kk0 + sl,
                       (char*)SH + 32768 + b * 16384 + w * 4096 + it * 1024);
        }
    };

    STAGE(0, 0);
    __syncthreads();
    int cur = 0;

    for (int ks = 0; ks < KSTEPS; ++ks) {
        if (ks + 1 < KSTEPS) STAGE(cur ^ 1, ks + 1);

        const char* Ab = (const char*)SH + cur * 16384;
        const char* Wb = (const char*)SH + 32768 + cur * 16384;
        bf16x8 af[4][2], bfr[4][2];
#pragma unroll
        for (int mf = 0; mf < 4; ++mf)
#pragma unroll
            for (int kk = 0; kk < 2; ++kk) {
                int r = m0 + mf * 16 + (lane & 15);
                int sl = (kk * 4 + (lane >> 4)) ^ (r & 7);
                af[mf][kk] = *(const bf16x8*)(Ab + r * 128 + sl * 16);
            }
#pragma unroll
        for (int nf = 0; nf < 4; ++nf)
#pragma unroll
            for (int kk = 0; kk < 2; ++kk) {
                int r = n0 + nf * 16 + (lane & 15);
                int sl = (kk * 4 + (lane >> 4)) ^ (r & 7);
                bfr[nf][kk] = *(const bf16x8*)(Wb + r * 128 + sl * 16);
            }
#pragma unroll
        for (int mf = 0; mf < 4; ++mf)
#pragma unroll
            for (int nf = 0; nf < 4; ++nf)
#pragma unroll
                for (int kk = 0; kk < 2; ++kk)
                    acc[mf][nf] = __builtin_amdgcn_mfma_f32_16x16x32_bf16(
                        af[mf][kk], bfr[nf][kk], acc[mf][nf], 0, 0, 0);
        __syncthreads();
        cur ^= 1;
    }

    const bool do8 = (FP8W > 0) && (colb < FP8W);

    // epilogue: C/D layout col=lane&15, row=(lane>>4)*4+reg
#pragma unroll
    for (int mf = 0; mf < 4; ++mf) {
#pragma unroll
        for (int nf = 0; nf < 4; ++nf) {
            int cl = n0 + nf * 16 + (lane & 15);
            int c = colb + cl;
            float bv = 0.f;
            if constexpr (BIAS) bv = bias[c];
#pragma unroll
            for (int r = 0; r < 4; ++r) {
                int ml = m0 + mf * 16 + ((lane >> 4) << 2) + r;
                int m = row0 + ml;
                if (m < M) {
                    float v = acc[mf][nf][r] + bv;
                    if constexpr (RELU) v = fmaxf(v, 0.f);
                    unsigned short bf = f2bf(v);
                    C[(size_t)m * ldc + coff + c] = bf;
                    if constexpr (FP8W > 0)
                        if (do8) SH[ml * 136 + cl] = bf;
                }
            }
        }
    }

    if constexpr (FP8W > 0) {
        if (do8) {
            __syncthreads();
#pragma unroll
            for (int q0 = 0; q0 < 1024; q0 += 256) {
                int q = q0 + tid;
                int row = q >> 3;
                int m = row0 + row;
                if (m < M) {
                    int cg = (q & 7) << 4;
                    const unsigned short* tp = SH + row * 136 + cg;
                    uint4 w0 = *(const uint4*)tp;
                    uint4 w1 = *(const uint4*)(tp + 8);
                    uint4 o;
                    o.x = pack4fp8(bf_lo(w0.x), bf_hi(w0.x), bf_lo(w0.y), bf_hi(w0.y));
                    o.y = pack4fp8(bf_lo(w0.z), bf_hi(w0.z), bf_lo(w0.w), bf_hi(w0.w));
                    o.z = pack4fp8(bf_lo(w1.x), bf_hi(w1.x), bf_lo(w1.y), bf_hi(w1.y));
                    o.w = pack4fp8(bf_lo(w1.z), bf_hi(w1.z), bf_lo(w1.w), bf_hi(w1.w));
                    *(uint4*)&fp8out[(size_t)m * FP8W + colb + cg] = o;
                }
            }
        }
    }
}

// ---------------------------------------------------------------------------
// Fused final: gather (fp8 t3l) + relu(agg3+b3+t3r) + per-graph pool.
// ---------------------------------------------------------------------------
__global__ __launch_bounds__(256) void k_final8(const unsigned char* __restrict__ t3l8,
                                                const unsigned short* __restrict__ t3,
                                                const float* __restrict__ b3,
                                                const int* __restrict__ offs,
                                                const unsigned short* __restrict__ deg,
                                                const unsigned short* __restrict__ ssrc,
                                                const int* __restrict__ batch,
                                                float* __restrict__ out) {
    __shared__ float sm[16][128];
    __shared__ int bsh[16];
    const int t = threadIdx.x;
    const int sub = t >> 4;
    const int f8 = (t & 15) * 8;
    const int n = blockIdx.x * 16 + sub;

    int s0 = offs[n];
    int d = deg[n];
    int pd = (d + 3) & ~3;
    float a[8];
#pragma unroll
    for (int j = 0; j < 8; ++j) a[j] = 0.f;
    const unsigned char* inf = t3l8 + f8;
    for (int i = s0; i < s0 + pd; i += 4) {
        int e0 = ssrc[i], e1 = ssrc[i + 1], e2 = ssrc[i + 2], e3 = ssrc[i + 3];
        uint2 v0 = *(const uint2*)&inf[(size_t)e0 * 128];
        uint2 v1 = *(const uint2*)&inf[(size_t)e1 * 128];
        uint2 v2 = *(const uint2*)&inf[(size_t)e2 * 128];
        uint2 v3 = *(const uint2*)&inf[(size_t)e3 * 128];
        DEC_ADD(v0.x, 0) DEC_ADD(v0.y, 4)
        DEC_ADD(v1.x, 0) DEC_ADD(v1.y, 4)
        DEC_ADD(v2.x, 0) DEC_ADD(v2.y, 4)
        DEC_ADD(v3.x, 0) DEC_ADD(v3.y, 4)
    }
    float scl = (d > 0) ? 1.f / (float)d : 0.f;
    float4 bv0 = *(const float4*)&b3[f8];
    float4 bv1 = *(const float4*)&b3[f8 + 4];
    uint4 tr = *(const uint4*)&t3[(size_t)n * 256 + 128 + f8];
    float tv[8] = {bf_lo(tr.x), bf_hi(tr.x), bf_lo(tr.y), bf_hi(tr.y),
                   bf_lo(tr.z), bf_hi(tr.z), bf_lo(tr.w), bf_hi(tr.w)};
    float bb[8] = {bv0.x, bv0.y, bv0.z, bv0.w, bv1.x, bv1.y, bv1.z, bv1.w};
#pragma unroll
    for (int j = 0; j < 8; ++j)
        sm[sub][f8 + j] = fmaxf(a[j] * scl + bb[j] + tv[j], 0.f);
    if ((t & 15) == 0) bsh[sub] = batch[n];
    __syncthreads();

    if (t < 128) {
        float local = 0.f;
        int cur = -1;
#pragma unroll
        for (int k = 0; k < 16; ++k) {
            int b = bsh[k];
            if (b != cur) {
                if (cur >= 0) atomicAdd(&out[(size_t)cur * 128 + t], local);
                local = 0.f;
                cur = b;
            }
            local += sm[k][t];
        }
        if (cur >= 0) atomicAdd(&out[(size_t)cur * 128 + t], local);
    }
}

// ---------------------------------------------------------------------------
extern "C" void kernel_launch(void* const* d_in, const int* in_sizes, int n_in,
                              void* d_out, int out_size, void* d_ws, size_t ws_size,
                              hipStream_t stream) {
    const float* x   = (const float*)d_in[0];
    const int* ei    = (const int*)d_in[1];
    const int* batch = (const int*)d_in[2];
    const float* W1l = (const float*)d_in[3];
    const float* b1  = (const float*)d_in[4];
    const float* W1r = (const float*)d_in[5];
    const float* W2l = (const float*)d_in[6];
    const float* b2  = (const float*)d_in[7];
    const float* W2r = (const float*)d_in[8];
    const float* W3l = (const float*)d_in[9];
    const float* b3  = (const float*)d_in[10];
    const float* W3r = (const float*)d_in[11];
    const int* src = ei;
    const int* dst = ei + N_EDGES;
    float* out = (float*)d_out;

    size_t off = 0;
    auto carve = [&](size_t bytes) {
        void* p = (char*)d_ws + off;
        off += (bytes + 255) & ~(size_t)255;
        return p;
    };
    int* gcnt   = (int*)carve(256 * 4);
    int* offs   = (int*)carve((size_t)N_NODES * 4);
    unsigned short* deg  = (unsigned short*)carve((size_t)N_NODES * 2);
    unsigned short* ssrc = (unsigned short*)carve((size_t)(N_EDGES + NBKT * 3 * BKT_NODES) * 2);
    unsigned short* A1   = (unsigned short*)carve((size_t)N_NODES * 256 * 2);  // [agg1|x]
    unsigned short* A2   = (unsigned short*)carve((size_t)N_NODES * 512 * 2);  // [agg2|h1]
    unsigned short* A3   = (unsigned short*)carve((size_t)N_NODES * 256 * 2);  // h2
    // t3 region doubles as bucketed edge staging (dead before gemm3 writes t3)
    void* t3region = carve((size_t)N_NODES * 256 * 2);  // 25.6MB >= 250*7168*4
    unsigned int* bucketed = (unsigned int*)t3region;
    unsigned short* t3 = (unsigned short*)t3region;
    unsigned char* x8   = (unsigned char*)carve((size_t)(N_NODES + 1) * 128);
    unsigned char* h18  = (unsigned char*)carve((size_t)(N_NODES + 1) * 256);
    unsigned char* t3l8 = (unsigned char*)carve((size_t)(N_NODES + 1) * 128);
    unsigned short* Wp1 = (unsigned short*)carve((size_t)256 * 256 * 2);
    unsigned short* Wp2 = (unsigned short*)carve((size_t)256 * 512 * 2);
    unsigned short* Wp3 = (unsigned short*)carve((size_t)256 * 256 * 2);

    hipMemsetAsync(gcnt, 0, 256 * 4, stream);
    hipMemsetAsync(d_out, 0, (size_t)out_size * 4, stream);
    // zero rows for gather padding
    hipMemsetAsync(x8 + (size_t)ZROW * 128, 0, 128, stream);
    hipMemsetAsync(h18 + (size_t)ZROW * 256, 0, 256, stream);
    hipMemsetAsync(t3l8 + (size_t)ZROW * 128, 0, 128, stream);

    // CSR build + converts
    k_front<<<NBB + NCVX + NCVW, 256, 0, stream>>>(src, dst, bucketed, gcnt,
                                                   x, A1 + 128, x8,
                                                   W1l, W1r, W2l, W2r, W3l, W3r,
                                                   Wp1, Wp2, Wp3);
    k_place<<<NBKT, 512, 0, stream>>>(bucketed, gcnt, offs, deg, ssrc);

    const dim3 ggrid((N_NODES + 127) / 128, 2);

    // L1: agg1 = mean(x8[src]); h1 = relu([agg1|x]@Wp1^T+b1) -> A2 right + h18 fp8
    k_gather8<128><<<(N_NODES + 31) / 32, 256, 0, stream>>>(x8, A1, 256, offs, deg, ssrc);
    k_gemm_mfma<4, true, true, 256><<<ggrid, 256, 0, stream>>>(A1, Wp1, b1, A2, 512, 256, h18, N_NODES);

    // L2: agg2 = mean(h18[src]); h2 = relu([agg2|h1]@Wp2^T+b2) -> A3
    k_gather8<256><<<(N_NODES + 15) / 16, 256, 0, stream>>>(h18, A2, 512, offs, deg, ssrc);
    k_gemm_mfma<8, true, true, 0><<<ggrid, 256, 0, stream>>>(A2, Wp2, b2, A3, 256, 0, nullptr, N_NODES);

    // L3: t3 = h2 @ [W3l;W3r]^T (left half also as fp8 t3l8); fused gather+pool
    k_gemm_mfma<4, false, false, 128><<<ggrid, 256, 0, stream>>>(A3, Wp3, nullptr, t3, 256, 0, t3l8, N_NODES);
    k_final8<<<N_NODES / 16, 256, 0, stream>>>(t3l8, t3, b3, offs, deg, ssrc, batch, out);
}

// Round 9
// 314.134 us; speedup vs baseline: 5.4164x; 1.0180x over previous
//
#include <hip/hip_runtime.h>
#include <hip/hip_bf16.h>

#define N_NODES 50000
#define N_EDGES 1600000
#define N_GRAPHS 64

// bucket sort geometry
#define NBKT 250          // buckets of 200 nodes each
#define BKT_NODES 200
#define BKT_CAP 7168      // mean 6400, sigma ~80; +9.6 sigma; guard-checked
#define CHUNK 4096        // edges per k_front bucket block
#define NBB 391           // ceil(1600000/4096)
#define NCVX 6250         // x-convert blocks
#define NCVW 256          // weight-convert blocks
#define ZROW N_NODES      // zero-row index for gather padding

typedef short bf16x8 __attribute__((ext_vector_type(8)));
typedef float f32x4 __attribute__((ext_vector_type(4)));
typedef float f32x2 __attribute__((ext_vector_type(2)));

__device__ __forceinline__ float bf_lo(unsigned int u) { return __uint_as_float(u << 16); }
__device__ __forceinline__ float bf_hi(unsigned int u) { return __uint_as_float(u & 0xffff0000u); }
__device__ __forceinline__ unsigned short f2bf(float f) {
    unsigned int u = __float_as_uint(f);
    u = (u + 0x7fffu + ((u >> 16) & 1u)) >> 16;
    return (unsigned short)u;
}
__device__ __forceinline__ unsigned int pack2bf(float a, float b) {
    return (unsigned int)f2bf(a) | ((unsigned int)f2bf(b) << 16);
}
__device__ __forceinline__ unsigned int pack4fp8(float a, float b, float c, float d) {
    unsigned int q = __builtin_amdgcn_cvt_pk_fp8_f32(a, b, 0, false);
    q = __builtin_amdgcn_cvt_pk_fp8_f32(c, d, q, true);
    return q;
}
__device__ __forceinline__ void load_lds16(const void* g, void* l) {
    __builtin_amdgcn_global_load_lds(
        (const __attribute__((address_space(1))) void*)g,
        (__attribute__((address_space(3))) void*)l, 16, 0, 0);
}

// ---------------------------------------------------------------------------
// k_front: fused {edge bucketing | x->bf16+fp8 convert | weight converts}
// First convert block also writes the ZROW zero rows (replaces 3 memsets).
// ---------------------------------------------------------------------------
__global__ __launch_bounds__(256) void k_front(
    const int* __restrict__ src, const int* __restrict__ dst,
    unsigned int* __restrict__ bucketed, int* __restrict__ gcnt,
    const float* __restrict__ x, unsigned short* __restrict__ A1x,
    unsigned char* __restrict__ x8, unsigned char* __restrict__ h18,
    unsigned char* __restrict__ t3l8,
    const float* __restrict__ W1l, const float* __restrict__ W1r,
    const float* __restrict__ W2l, const float* __restrict__ W2r,
    const float* __restrict__ W3l, const float* __restrict__ W3r,
    unsigned short* __restrict__ Wp1, unsigned short* __restrict__ Wp2,
    unsigned short* __restrict__ Wp3) {
    const int blk = blockIdx.x;
    const int t = threadIdx.x;

    if (blk < NBB) {
        __shared__ int lcnt[256];
        __shared__ int sc[256];
        __shared__ int lscan[256];
        __shared__ int gb[256];
        __shared__ unsigned int grouped[CHUNK];

        const int base = blk * CHUNK;
        const int ccnt = min(CHUNK, N_EDGES - base);
        lcnt[t] = 0;
        __syncthreads();

        unsigned int pk[CHUNK / 256];
        int rk[CHUNK / 256];
#pragma unroll
        for (int r = 0; r < CHUNK / 256; ++r) {
            int j = r * 256 + t;
            rk[r] = -1;
            if (j < ccnt) {
                int i = base + j;
                int s = src[i];
                int d = dst[i];
                int b = d / BKT_NODES;
                int dl = d - b * BKT_NODES;
                pk[r] = (unsigned int)s | ((unsigned int)dl << 16) | ((unsigned int)b << 24);
                rk[r] = atomicAdd(&lcnt[b], 1);
            }
        }
        __syncthreads();
        sc[t] = lcnt[t];
        __syncthreads();
        for (int off = 1; off < 256; off <<= 1) {
            int v = (t >= off) ? sc[t - off] : 0;
            __syncthreads();
            sc[t] += v;
            __syncthreads();
        }
        lscan[t] = sc[t] - lcnt[t];
        if (t < NBKT && lcnt[t] > 0) gb[t] = atomicAdd(&gcnt[t], lcnt[t]);
        __syncthreads();
#pragma unroll
        for (int r = 0; r < CHUNK / 256; ++r) {
            if (rk[r] >= 0) {
                int b = pk[r] >> 24;
                grouped[lscan[b] + rk[r]] = pk[r];
            }
        }
        __syncthreads();
#pragma unroll
        for (int r = 0; r < CHUNK / 256; ++r) {
            int j = r * 256 + t;
            if (j < ccnt) {
                unsigned int v = grouped[j];
                int b = v >> 24;
                int pos = gb[b] + (j - lscan[b]);
                if (pos < BKT_CAP) bucketed[b * BKT_CAP + pos] = v;
            }
        }
    } else if (blk < NBB + NCVX) {
        // ---- x -> bf16 (A1 right half, stride 256) + fp8 ([.][128]) ----
        int i = (blk - NBB) * 256 + t;  // exactly 1.6M units of 4 floats
        int r = i >> 5;
        int f4 = (i & 31) << 2;
        float4 v = *(const float4*)&x[(size_t)r * 128 + f4];
        uint2 o;
        o.x = pack2bf(v.x, v.y);
        o.y = pack2bf(v.z, v.w);
        *(uint2*)&A1x[(size_t)r * 256 + f4] = o;
        *(unsigned int*)&x8[(size_t)r * 128 + f4] = pack4fp8(v.x, v.y, v.z, v.w);
        // zero rows for gather padding (once)
        if (blk == NBB && t < 32) {
            uint4 z = make_uint4(0, 0, 0, 0);
            if (t < 8) *(uint4*)&x8[(size_t)ZROW * 128 + t * 16] = z;
            else if (t < 24) *(uint4*)&h18[(size_t)ZROW * 256 + (t - 8) * 16] = z;
            else *(uint4*)&t3l8[(size_t)ZROW * 128 + (t - 24) * 16] = z;
        }
    } else {
        // ---- all 6 weight matrices -> packed bf16 ----
        int i = (blk - NBB - NCVX) * 256 + t;  // 0..65535
        const float* srcp;
        unsigned short* dstp;
        int sf4, dstride;
        if (i < 16384) {
            int h = i >> 13;
            i &= 8191;
            srcp = h ? W1r : W1l;
            dstp = Wp1 + (h ? 128 : 0);
            sf4 = 32; dstride = 256;
        } else if (i < 49152) {
            int j = i - 16384;
            int h = j >> 14;
            i = j & 16383;
            srcp = h ? W2r : W2l;
            dstp = Wp2 + (h ? 256 : 0);
            sf4 = 64; dstride = 512;
        } else {
            int j = i - 49152;
            int h = j >> 13;
            i = j & 8191;
            srcp = h ? W3r : W3l;
            dstp = Wp3 + (h ? 128 * 256 : 0);
            sf4 = 64; dstride = 256;
        }
        int r = i / sf4;
        int f4 = (i % sf4) * 4;
        float4 v = *(const float4*)&srcp[(size_t)r * (sf4 * 4) + f4];
        uint2 o;
        o.x = pack2bf(v.x, v.y);
        o.y = pack2bf(v.z, v.w);
        *(uint2*)&dstp[(size_t)r * dstride + f4] = o;
    }
}

// ---------------------------------------------------------------------------
// k_place: one block (512 thr) per bucket. Slack-scan (x4-rounded) of bucket
// counts -> x4-aligned global starts; LDS counting sort -> offs/deg + padded
// ssrc (segments padded to x4 with ZROW).
// ---------------------------------------------------------------------------
__global__ __launch_bounds__(512) void k_place(const unsigned int* __restrict__ bucketed,
                                               const int* __restrict__ gcnt,
                                               int* __restrict__ offs,
                                               unsigned short* __restrict__ deg,
                                               unsigned short* __restrict__ ssrc) {
    __shared__ unsigned int ent[BKT_CAP];
    __shared__ unsigned short rks[BKT_CAP];
    __shared__ int lcnt[256];
    __shared__ int sc[256];
    __shared__ int lofs[256];
    __shared__ int gs;

    const int b = blockIdx.x;
    const int t = threadIdx.x;

    // slack scan (inclusive) over x4-rounded per-bucket upper bounds
    if (t < 256) sc[t] = (t < NBKT) ? (((gcnt[t] + 3) & ~3) + 3 * BKT_NODES) : 0;
    __syncthreads();
    for (int off = 1; off < 256; off <<= 1) {
        int u = 0;
        if (t < 256 && t >= off) u = sc[t - off];
        __syncthreads();
        if (t < 256) sc[t] += u;
        __syncthreads();
    }
    if (t == 0) gs = (b == 0) ? 0 : sc[b - 1];
    if (t < 256) lcnt[t] = 0;
    __syncthreads();

    const int cnt = min(gcnt[b], BKT_CAP);
    const unsigned int* eg = bucketed + (size_t)b * BKT_CAP;
    for (int i = t; i < cnt; i += 512) {
        unsigned int v = eg[i];
        ent[i] = v;
        int dl = (v >> 16) & 0xFF;
        rks[i] = (unsigned short)atomicAdd(&lcnt[dl], 1);
    }
    __syncthreads();
    // padded exclusive scan of per-node counts
    int pc = 0;
    if (t < 256) {
        pc = (lcnt[t] + 3) & ~3;
        sc[t] = pc;
    }
    __syncthreads();
    for (int off = 1; off < 256; off <<= 1) {
        int u = 0;
        if (t < 256 && t >= off) u = sc[t - off];
        __syncthreads();
        if (t < 256) sc[t] += u;
        __syncthreads();
    }
    if (t < 256) lofs[t] = sc[t] - pc;
    __syncthreads();
    const int gstart = gs;
    if (t < BKT_NODES) {
        offs[b * BKT_NODES + t] = gstart + lofs[t];
        deg[b * BKT_NODES + t] = (unsigned short)lcnt[t];
    }
    for (int i = t; i < cnt; i += 512) {
        unsigned int v = ent[i];
        int dl = (v >> 16) & 0xFF;
        ssrc[gstart + lofs[dl] + (int)rks[i]] = (unsigned short)(v & 0xFFFF);
    }
    if (t < BKT_NODES) {
        int d = lcnt[t], pd = (d + 3) & ~3;
        int base = gstart + lofs[t];
        for (int j = d; j < pd; ++j) ssrc[base + j] = (unsigned short)ZROW;
    }
}

// ---------------------------------------------------------------------------
// fp8 gather-mean -> bf16. Padded x4 segments, x4-aligned starts (ushort4
// index loads), 2-deep register pipeline (prefetch next 4 rows while
// accumulating current 4).
// ---------------------------------------------------------------------------
#define DEC_ADD(dw, base)                                             \
    {                                                                 \
        f32x2 lo_ = __builtin_amdgcn_cvt_pk_f32_fp8((dw), false);     \
        f32x2 hi_ = __builtin_amdgcn_cvt_pk_f32_fp8((dw), true);      \
        a[(base) + 0] += lo_.x;                                       \
        a[(base) + 1] += lo_.y;                                       \
        a[(base) + 2] += hi_.x;                                       \
        a[(base) + 3] += hi_.y;                                       \
    }
#define DEC_ADD4(v) { DEC_ADD((v).x, 0) DEC_ADD((v).y, 4) DEC_ADD((v).z, 8) DEC_ADD((v).w, 12) }

template <int F>
__global__ __launch_bounds__(256) void k_gather8(const unsigned char* __restrict__ in,
                                                 unsigned short* __restrict__ out,
                                                 int ostride,
                                                 const int* __restrict__ offs,
                                                 const unsigned short* __restrict__ deg,
                                                 const unsigned short* __restrict__ ssrc) {
    constexpr int TPN = F / 16;
    constexpr int NPB = 256 / TPN;
    int n = blockIdx.x * NPB + threadIdx.x / TPN;
    int f16 = (threadIdx.x % TPN) * 16;
    if (n >= N_NODES) return;
    int s0 = offs[n];
    int d = deg[n];
    int pd = (d + 3) & ~3;
    float a[16];
#pragma unroll
    for (int j = 0; j < 16; ++j) a[j] = 0.f;
    const unsigned char* inf = in + f16;
    if (pd > 0) {
        ushort4 es = *(const ushort4*)&ssrc[s0];
        uint4 c0 = *(const uint4*)&inf[(size_t)es.x * F];
        uint4 c1 = *(const uint4*)&inf[(size_t)es.y * F];
        uint4 c2 = *(const uint4*)&inf[(size_t)es.z * F];
        uint4 c3 = *(const uint4*)&inf[(size_t)es.w * F];
        for (int i = s0 + 4; i < s0 + pd; i += 4) {
            ushort4 ns = *(const ushort4*)&ssrc[i];
            uint4 n0 = *(const uint4*)&inf[(size_t)ns.x * F];
            uint4 n1 = *(const uint4*)&inf[(size_t)ns.y * F];
            uint4 n2 = *(const uint4*)&inf[(size_t)ns.z * F];
            uint4 n3 = *(const uint4*)&inf[(size_t)ns.w * F];
            DEC_ADD4(c0) DEC_ADD4(c1) DEC_ADD4(c2) DEC_ADD4(c3)
            c0 = n0; c1 = n1; c2 = n2; c3 = n3;
        }
        DEC_ADD4(c0) DEC_ADD4(c1) DEC_ADD4(c2) DEC_ADD4(c3)
    }
    float scl = (d > 0) ? 1.f / (float)d : 0.f;
    uint4 o0, o1;
    o0.x = pack2bf(a[0] * scl, a[1] * scl);
    o0.y = pack2bf(a[2] * scl, a[3] * scl);
    o0.z = pack2bf(a[4] * scl, a[5] * scl);
    o0.w = pack2bf(a[6] * scl, a[7] * scl);
    o1.x = pack2bf(a[8] * scl, a[9] * scl);
    o1.y = pack2bf(a[10] * scl, a[11] * scl);
    o1.z = pack2bf(a[12] * scl, a[13] * scl);
    o1.w = pack2bf(a[14] * scl, a[15] * scl);
    *(uint4*)&out[(size_t)n * ostride + f16] = o0;
    *(uint4*)&out[(size_t)n * ostride + f16 + 8] = o1;
}

// ---------------------------------------------------------------------------
// bf16 MFMA GEMM (128x128 tile, 4 waves, BK=64, dbuf 2-phase, XOR-swizzle).
// C[m][coff+n] = op(A[m,:].W[n,:] + bias[n]).  FP8W>0: also emit fp8 copy
// into fp8out (row width FP8W) via LDS transpose.
// ---------------------------------------------------------------------------
template <int KSTEPS, bool RELU, bool BIAS, int FP8W>
__global__ __launch_bounds__(256) void k_gemm_mfma(const unsigned short* __restrict__ A,
                                                   const unsigned short* __restrict__ W,
                                                   const float* __restrict__ bias,
                                                   unsigned short* __restrict__ C,
                                                   int ldc, int coff,
                                                   unsigned char* __restrict__ fp8out,
                                                   int M) {
    constexpr int K = KSTEPS * 64;
    __shared__ unsigned short SH[32768];  // As0|As1|Ws0|Ws1 (16KB each)

    const int tid = threadIdx.x;
    const int lane = tid & 63;
    const int w = tid >> 6;
    const int row0 = blockIdx.x * 128;
    const int colb = blockIdx.y * 128;

    const int srow_b = w * 32 + (lane >> 3);
    const int slot = lane & 7;

    f32x4 acc[4][4];
#pragma unroll
    for (int i = 0; i < 4; ++i)
#pragma unroll
        for (int j = 0; j < 4; ++j) acc[i][j] = (f32x4){0.f, 0.f, 0.f, 0.f};

    const int m0 = (w >> 1) * 64;
    const int n0 = (w & 1) * 64;

    auto STAGE = [&](int b, int ks) {
        const int kk0 = ks * 64;
#pragma unroll
        for (int it = 0; it < 4; ++it) {
            int r = srow_b + it * 8;
            int sl = (slot ^ (r & 7)) << 3;
            int ra = min(row0 + r, M - 1);
            load_lds16(A + (size_t)ra * K + kk0 + sl,
                       (char*)SH + b * 16384 + w * 4096 + it * 1024);
            load_lds16(W + (size_t)(colb + r) * K + kk0 + sl,
                       (char*)SH + 32768 + b * 16384 + w * 4096 + it * 1024);
        }
    };

    STAGE(0, 0);
    __syncthreads();
    int cur = 0;

    for (int ks = 0; ks < KSTEPS; ++ks) {
        if (ks + 1 < KSTEPS) STAGE(cur ^ 1, ks + 1);

        const char* Ab = (const char*)SH + cur * 16384;
        const char* Wb = (const char*)SH + 32768 + cur * 16384;
        bf16x8 af[4][2], bfr[4][2];
#pragma unroll
        for (int mf = 0; mf < 4; ++mf)
#pragma unroll
            for (int kk = 0; kk < 2; ++kk) {
                int r = m0 + mf * 16 + (lane & 15);
                int sl = (kk * 4 + (lane >> 4)) ^ (r & 7);
                af[mf][kk] = *(const bf16x8*)(Ab + r * 128 + sl * 16);
            }
#pragma unroll
        for (int nf = 0; nf < 4; ++nf)
#pragma unroll
            for (int kk = 0; kk < 2; ++kk) {
                int r = n0 + nf * 16 + (lane & 15);
                int sl = (kk * 4 + (lane >> 4)) ^ (r & 7);
                bfr[nf][kk] = *(const bf16x8*)(Wb + r * 128 + sl * 16);
            }
#pragma unroll
        for (int mf = 0; mf < 4; ++mf)
#pragma unroll
            for (int nf = 0; nf < 4; ++nf)
#pragma unroll
                for (int kk = 0; kk < 2; ++kk)
                    acc[mf][nf] = __builtin_amdgcn_mfma_f32_16x16x32_bf16(
                        af[mf][kk], bfr[nf][kk], acc[mf][nf], 0, 0, 0);
        __syncthreads();
        cur ^= 1;
    }

    const bool do8 = (FP8W > 0) && (colb < FP8W);

    // epilogue: C/D layout col=lane&15, row=(lane>>4)*4+reg
#pragma unroll
    for (int mf = 0; mf < 4; ++mf) {
#pragma unroll
        for (int nf = 0; nf < 4; ++nf) {
            int cl = n0 + nf * 16 + (lane & 15);
            int c = colb + cl;
            float bv = 0.f;
            if constexpr (BIAS) bv = bias[c];
#pragma unroll
            for (int r = 0; r < 4; ++r) {
                int ml = m0 + mf * 16 + ((lane >> 4) << 2) + r;
                int m = row0 + ml;
                if (m < M) {
                    float v = acc[mf][nf][r] + bv;
                    if constexpr (RELU) v = fmaxf(v, 0.f);
                    unsigned short bf = f2bf(v);
                    C[(size_t)m * ldc + coff + c] = bf;
                    if constexpr (FP8W > 0)
                        if (do8) SH[ml * 136 + cl] = bf;
                }
            }
        }
    }

    if constexpr (FP8W > 0) {
        if (do8) {
            __syncthreads();
#pragma unroll
            for (int q0 = 0; q0 < 1024; q0 += 256) {
                int q = q0 + tid;
                int row = q >> 3;
                int m = row0 + row;
                if (m < M) {
                    int cg = (q & 7) << 4;
                    const unsigned short* tp = SH + row * 136 + cg;
                    uint4 w0 = *(const uint4*)tp;
                    uint4 w1 = *(const uint4*)(tp + 8);
                    uint4 o;
                    o.x = pack4fp8(bf_lo(w0.x), bf_hi(w0.x), bf_lo(w0.y), bf_hi(w0.y));
                    o.y = pack4fp8(bf_lo(w0.z), bf_hi(w0.z), bf_lo(w0.w), bf_hi(w0.w));
                    o.z = pack4fp8(bf_lo(w1.x), bf_hi(w1.x), bf_lo(w1.y), bf_hi(w1.y));
                    o.w = pack4fp8(bf_lo(w1.z), bf_hi(w1.z), bf_lo(w1.w), bf_hi(w1.w));
                    *(uint4*)&fp8out[(size_t)m * FP8W + colb + cg] = o;
                }
            }
        }
    }
}

// ---------------------------------------------------------------------------
// Fused final: pipelined gather (fp8 t3l) + relu(agg3+b3+t3r) + per-graph pool.
// ---------------------------------------------------------------------------
__global__ __launch_bounds__(256) void k_final8(const unsigned char* __restrict__ t3l8,
                                                const unsigned short* __restrict__ t3,
                                                const float* __restrict__ b3,
                                                const int* __restrict__ offs,
                                                const unsigned short* __restrict__ deg,
                                                const unsigned short* __restrict__ ssrc,
                                                const int* __restrict__ batch,
                                                float* __restrict__ out) {
    __shared__ float sm[16][128];
    __shared__ int bsh[16];
    const int t = threadIdx.x;
    const int sub = t >> 4;
    const int f8 = (t & 15) * 8;
    const int n = blockIdx.x * 16 + sub;

    int s0 = offs[n];
    int d = deg[n];
    int pd = (d + 3) & ~3;
    float a[8];
#pragma unroll
    for (int j = 0; j < 8; ++j) a[j] = 0.f;
    const unsigned char* inf = t3l8 + f8;
    if (pd > 0) {
        ushort4 es = *(const ushort4*)&ssrc[s0];
        uint2 c0 = *(const uint2*)&inf[(size_t)es.x * 128];
        uint2 c1 = *(const uint2*)&inf[(size_t)es.y * 128];
        uint2 c2 = *(const uint2*)&inf[(size_t)es.z * 128];
        uint2 c3 = *(const uint2*)&inf[(size_t)es.w * 128];
        for (int i = s0 + 4; i < s0 + pd; i += 4) {
            ushort4 ns = *(const ushort4*)&ssrc[i];
            uint2 n0 = *(const uint2*)&inf[(size_t)ns.x * 128];
            uint2 n1 = *(const uint2*)&inf[(size_t)ns.y * 128];
            uint2 n2 = *(const uint2*)&inf[(size_t)ns.z * 128];
            uint2 n3 = *(const uint2*)&inf[(size_t)ns.w * 128];
            DEC_ADD(c0.x, 0) DEC_ADD(c0.y, 4)
            DEC_ADD(c1.x, 0) DEC_ADD(c1.y, 4)
            DEC_ADD(c2.x, 0) DEC_ADD(c2.y, 4)
            DEC_ADD(c3.x, 0) DEC_ADD(c3.y, 4)
            c0 = n0; c1 = n1; c2 = n2; c3 = n3;
        }
        DEC_ADD(c0.x, 0) DEC_ADD(c0.y, 4)
        DEC_ADD(c1.x, 0) DEC_ADD(c1.y, 4)
        DEC_ADD(c2.x, 0) DEC_ADD(c2.y, 4)
        DEC_ADD(c3.x, 0) DEC_ADD(c3.y, 4)
    }
    float scl = (d > 0) ? 1.f / (float)d : 0.f;
    float4 bv0 = *(const float4*)&b3[f8];
    float4 bv1 = *(const float4*)&b3[f8 + 4];
    uint4 tr = *(const uint4*)&t3[(size_t)n * 256 + 128 + f8];
    float tv[8] = {bf_lo(tr.x), bf_hi(tr.x), bf_lo(tr.y), bf_hi(tr.y),
                   bf_lo(tr.z), bf_hi(tr.z), bf_lo(tr.w), bf_hi(tr.w)};
    float bb[8] = {bv0.x, bv0.y, bv0.z, bv0.w, bv1.x, bv1.y, bv1.z, bv1.w};
#pragma unroll
    for (int j = 0; j < 8; ++j)
        sm[sub][f8 + j] = fmaxf(a[j] * scl + bb[j] + tv[j], 0.f);
    if ((t & 15) == 0) bsh[sub] = batch[n];
    __syncthreads();

    if (t < 128) {
        float local = 0.f;
        int cur = -1;
#pragma unroll
        for (int k = 0; k < 16; ++k) {
            int b = bsh[k];
            if (b != cur) {
                if (cur >= 0) atomicAdd(&out[(size_t)cur * 128 + t], local);
                local = 0.f;
                cur = b;
            }
            local += sm[k][t];
        }
        if (cur >= 0) atomicAdd(&out[(size_t)cur * 128 + t], local);
    }
}

// ---------------------------------------------------------------------------
extern "C" void kernel_launch(void* const* d_in, const int* in_sizes, int n_in,
                              void* d_out, int out_size, void* d_ws, size_t ws_size,
                              hipStream_t stream) {
    const float* x   = (const float*)d_in[0];
    const int* ei    = (const int*)d_in[1];
    const int* batch = (const int*)d_in[2];
    const float* W1l = (const float*)d_in[3];
    const float* b1  = (const float*)d_in[4];
    const float* W1r = (const float*)d_in[5];
    const float* W2l = (const float*)d_in[6];
    const float* b2  = (const float*)d_in[7];
    const float* W2r = (const float*)d_in[8];
    const float* W3l = (const float*)d_in[9];
    const float* b3  = (const float*)d_in[10];
    const float* W3r = (const float*)d_in[11];
    const int* src = ei;
    const int* dst = ei + N_EDGES;
    float* out = (float*)d_out;

    size_t off = 0;
    auto carve = [&](size_t bytes) {
        void* p = (char*)d_ws + off;
        off += (bytes + 255) & ~(size_t)255;
        return p;
    };
    int* gcnt   = (int*)carve(256 * 4);
    int* offs   = (int*)carve((size_t)N_NODES * 4);
    unsigned short* deg  = (unsigned short*)carve((size_t)N_NODES * 2);
    unsigned short* ssrc = (unsigned short*)carve((size_t)(N_EDGES + NBKT * 1024) * 2);
    unsigned short* A1   = (unsigned short*)carve((size_t)N_NODES * 256 * 2);  // [agg1|x]
    unsigned short* A2   = (unsigned short*)carve((size_t)N_NODES * 512 * 2);  // [agg2|h1]
    unsigned short* A3   = (unsigned short*)carve((size_t)N_NODES * 256 * 2);  // h2
    // t3 region doubles as bucketed edge staging (dead before gemm3 writes t3)
    void* t3region = carve((size_t)N_NODES * 256 * 2);  // 25.6MB >= 250*7168*4
    unsigned int* bucketed = (unsigned int*)t3region;
    unsigned short* t3 = (unsigned short*)t3region;
    unsigned char* x8   = (unsigned char*)carve((size_t)(N_NODES + 1) * 128);
    unsigned char* h18  = (unsigned char*)carve((size_t)(N_NODES + 1) * 256);
    unsigned char* t3l8 = (unsigned char*)carve((size_t)(N_NODES + 1) * 128);
    unsigned short* Wp1 = (unsigned short*)carve((size_t)256 * 256 * 2);
    unsigned short* Wp2 = (unsigned short*)carve((size_t)256 * 512 * 2);
    unsigned short* Wp3 = (unsigned short*)carve((size_t)256 * 256 * 2);

    hipMemsetAsync(gcnt, 0, 256 * 4, stream);
    hipMemsetAsync(d_out, 0, (size_t)out_size * 4, stream);

    // CSR build + converts (+ zero rows)
    k_front<<<NBB + NCVX + NCVW, 256, 0, stream>>>(src, dst, bucketed, gcnt,
                                                   x, A1 + 128, x8, h18, t3l8,
                                                   W1l, W1r, W2l, W2r, W3l, W3r,
                                                   Wp1, Wp2, Wp3);
    k_place<<<NBKT, 512, 0, stream>>>(bucketed, gcnt, offs, deg, ssrc);

    const dim3 ggrid((N_NODES + 127) / 128, 2);

    // L1: agg1 = mean(x8[src]); h1 = relu([agg1|x]@Wp1^T+b1) -> A2 right + h18 fp8
    k_gather8<128><<<(N_NODES + 31) / 32, 256, 0, stream>>>(x8, A1, 256, offs, deg, ssrc);
    k_gemm_mfma<4, true, true, 256><<<ggrid, 256, 0, stream>>>(A1, Wp1, b1, A2, 512, 256, h18, N_NODES);

    // L2: agg2 = mean(h18[src]); h2 = relu([agg2|h1]@Wp2^T+b2) -> A3
    k_gather8<256><<<(N_NODES + 15) / 16, 256, 0, stream>>>(h18, A2, 512, offs, deg, ssrc);
    k_gemm_mfma<8, true, true, 0><<<ggrid, 256, 0, stream>>>(A2, Wp2, b2, A3, 256, 0, nullptr, N_NODES);

    // L3: t3 = h2 @ [W3l;W3r]^T (left half also as fp8 t3l8); fused gather+pool
    k_gemm_mfma<4, false, false, 128><<<ggrid, 256, 0, stream>>>(A3, Wp3, nullptr, t3, 256, 0, t3l8, N_NODES);
    k_final8<<<N_NODES / 16, 256, 0, stream>>>(t3l8, t3, b3, offs, deg, ssrc, batch, out);
}